// Round 3
// baseline (565.706 us; speedup 1.0000x reference)
//
#include <hip/hip_runtime.h>

#define NN 100000
#define NE 800000
#define NPAD 100096  // 782*128 = 6256*16
#define OCT 12544    // 8*12544 = 100352 >= NN ; dst/OCT = XCD octant

typedef __attribute__((ext_vector_type(8))) __bf16 bf16x8;
typedef __attribute__((ext_vector_type(4))) float f32x4;

__device__ __forceinline__ uint f2bf(float f) {  // f32 -> bf16 bits (RNE), low 16
  uint u = __float_as_uint(f);
  return (u + 0x7fffu + ((u >> 16) & 1u)) >> 16;
}
__device__ __forceinline__ float bflo(uint u) { return __uint_as_float(u << 16); }
__device__ __forceinline__ float bfhi(uint u) { return __uint_as_float(u & 0xffff0000u); }

// ---------------- CSR build (XCD-partitioned hist/scatter) ----------------
__global__ __launch_bounds__(256) void k_hist(const int* __restrict__ dst,
                                              int* __restrict__ deg) {
  int xcd = blockIdx.x & 7, chunk = blockIdx.x >> 3;
  int e0 = chunk * 2048 + threadIdx.x;
#pragma unroll
  for (int i = 0; i < 8; ++i) {
    int e = e0 + i * 256;
    if (e < NE) {
      int d = dst[e];
      if (d / OCT == xcd) atomicAdd(&deg[d], 1);
    }
  }
}

__global__ void k_scan_partial(const int* __restrict__ deg, int* __restrict__ bsum, int N) {
  __shared__ int s[256];
  int b = blockIdx.x, t = threadIdx.x;
  int base = b * 1024 + t * 4;
  int v = 0;
#pragma unroll
  for (int i = 0; i < 4; ++i) { int idx = base + i; if (idx < N) v += deg[idx]; }
  s[t] = v; __syncthreads();
  for (int o = 128; o > 0; o >>= 1) { if (t < o) s[t] += s[t + o]; __syncthreads(); }
  if (t == 0) bsum[b] = s[0];
}

__global__ void k_scan_bsums(const int* __restrict__ bsum, int* __restrict__ bpre,
                             int* __restrict__ offsets, int NB, int N) {
  __shared__ int s[128];
  int t = threadIdx.x;
  int v = (t < NB) ? bsum[t] : 0;
  s[t] = v; __syncthreads();
  for (int o = 1; o < 128; o <<= 1) {
    int add = (t >= o) ? s[t - o] : 0;
    __syncthreads();
    s[t] += add;
    __syncthreads();
  }
  if (t < NB) bpre[t] = s[t] - v;
  if (t == NB - 1) offsets[N] = s[t];
}

__global__ void k_scan_final(const int* __restrict__ deg, const int* __restrict__ bpre,
                             int* __restrict__ offsets, int* __restrict__ cursor, int N) {
  __shared__ int s[256];
  int b = blockIdx.x, t = threadIdx.x;
  int base = b * 1024 + t * 4;
  int v[4];
#pragma unroll
  for (int i = 0; i < 4; ++i) { int idx = base + i; v[i] = (idx < N) ? deg[idx] : 0; }
  int tsum = v[0] + v[1] + v[2] + v[3];
  s[t] = tsum; __syncthreads();
  for (int o = 1; o < 256; o <<= 1) {
    int add = (t >= o) ? s[t - o] : 0;
    __syncthreads();
    s[t] += add;
    __syncthreads();
  }
  int run = s[t] - tsum + bpre[b];
#pragma unroll
  for (int i = 0; i < 4; ++i) {
    int idx = base + i;
    if (idx < N) { offsets[idx] = run; cursor[idx] = run; }
    run += v[i];
  }
}

__global__ __launch_bounds__(256) void k_scatter(const int* __restrict__ src,
                                                 const int* __restrict__ dst,
                                                 int* __restrict__ cursor,
                                                 int* __restrict__ csr_src) {
  int xcd = blockIdx.x & 7, chunk = blockIdx.x >> 3;
  int e0 = chunk * 2048 + threadIdx.x;
#pragma unroll
  for (int i = 0; i < 8; ++i) {
    int e = e0 + i * 256;
    if (e < NE) {
      int d = dst[e];
      if (d / OCT == xcd) {
        int pos = atomicAdd(&cursor[d], 1);
        csr_src[pos] = src[e];
      }
    }
  }
}

// ---------------- weight convert ----------------
// layout: [Wst1 256o x 128k = 32768][Wst2 256o x 256k = 65536][Wt3 32 x 256 = 8192]
// Wst1 stacked along OUT: o<128 -> Wrel1 col o (Y half) ; o>=128 -> Wroot1 col o-128 (Z half)
// Wst2 stacked along K:   k<128 -> Wrel2 ; k>=128 -> Wroot2
__global__ void k_cvt_w(const float* __restrict__ Wr1, const float* __restrict__ Wo1,
                        const float* __restrict__ Wr2, const float* __restrict__ Wo2,
                        const float* __restrict__ Wr3, const float* __restrict__ Wo3,
                        ushort* __restrict__ t) {
  int idx = blockIdx.x * 256 + threadIdx.x;
  if (idx >= 106496) return;
  float v;
  if (idx < 32768) {         // Wst1 [o<256][k<128]
    int o = idx >> 7, k = idx & 127;
    v = (o < 128) ? Wr1[(size_t)k * 128 + o] : Wo1[(size_t)k * 128 + (o - 128)];
  } else if (idx < 98304) {  // Wst2 [o<256][k<256]
    int li = idx - 32768;
    int o = li >> 8, k = li & 255;
    v = (k < 128) ? Wr2[(size_t)k * 256 + o] : Wo2[(size_t)(k - 128) * 256 + o];
  } else {                   // Wt3 [32][256]
    int li = idx - 98304;
    int o = li >> 8, k = li & 255;
    v = (o < 16) ? Wr3[(size_t)k * 16 + o] : Wo3[(size_t)k * 16 + (o - 16)];
  }
  t[idx] = (ushort)f2bf(v);
}

// ---------------- streaming MFMA GEMM ----------------
// 256 blocks (1/CU, forced by 128KB LDS), 8 waves. W staged to LDS ONCE (the only
// barrier); each wave then independently streams 16-row A-panels with a register
// ping-pong prefetch: load(t+1) || mfma(t) || store(t). No per-tile sync, no W restage.
// AF32=1: A is row-major f32 (X), converted to bf16 fragments in-register.
// AF32=0: A is bf16 panel layout: (row>>4)*(KD*32) + (k>>3)*256 + (row&15)*16 + (k&7)*2.
template <int KD, int OUTD, int AF32, int RELU, int BIAS>
__global__ __launch_bounds__(512, 1) void k_gemm_stream(
    const void* __restrict__ Ain, const ushort* __restrict__ Wst,
    const float* __restrict__ bias, ushort* __restrict__ out, int NP) {
  __shared__ ushort sW[65536];  // 128KB (gemm1 uses first 64KB; size forces 1 block/CU)
  int tid = threadIdx.x;
  int lane = tid & 63, wid = tid >> 6;
  int cl = lane & 15, hi = lane >> 4;
  constexpr int ROWB = KD * 2;        // W row bytes (256 or 512)
  constexpr int WB = OUTD * KD * 2;   // W total bytes (64KB or 128KB)
  constexpr int NJ = OUTD / 16;       // 16
  constexpr int NF = KD / 32;         // A frags per panel (4 or 8)

  const char* gw = (const char*)Wst;
#pragma unroll
  for (int i = 0; i < WB / 8192; ++i) {
    int L = (tid + i * 512) << 4;     // linear LDS byte
    int o = L / ROWB;
    int gb = L ^ ((o & 15) << 4);     // pre-swizzled global source (involution in-row)
    __builtin_amdgcn_global_load_lds((const __attribute__((address_space(1))) void*)(gw + gb),
                                     (__attribute__((address_space(3))) void*)((char*)sW + L), 16, 0, 0);
  }
  float bv[NJ];
#pragma unroll
  for (int j = 0; j < NJ; ++j) bv[j] = BIAS ? bias[j * 16 + cl] : 0.f;
  __syncthreads();  // the ONLY barrier: W resident for the rest of the kernel

  int g = blockIdx.x * 8 + wid;  // global wave id in [0, 2048)
  const int S = 2048;

  bf16x8 Ac[NF], An[NF];
  float4 Fc[AF32 ? 2 * NF : 1], Fn[AF32 ? 2 * NF : 1];

  // prologue load of panel g (g < NP always: NP >= 6250 > 2048)
  if constexpr (AF32) {
    const char* pb = (const char*)Ain + ((size_t)g * 16 + cl) * (KD * 4) + hi * 32;
#pragma unroll
    for (int ks = 0; ks < NF; ++ks) {
      Fc[2 * ks] = *(const float4*)(pb + ks * 128);
      Fc[2 * ks + 1] = *(const float4*)(pb + ks * 128 + 16);
    }
  } else {
    const char* pb = (const char*)Ain + (size_t)g * (KD * 32) + lane * 16;
#pragma unroll
    for (int ks = 0; ks < NF; ++ks) Ac[ks] = *(const bf16x8*)(pb + ks * 1024);
  }

  for (int t = g; t < NP; t += S) {
    int nt = t + S;
    bool pf = nt < NP;
    if (pf) {  // prefetch next panel (wave-uniform branch)
      if constexpr (AF32) {
        const char* pb = (const char*)Ain + ((size_t)nt * 16 + cl) * (KD * 4) + hi * 32;
#pragma unroll
        for (int ks = 0; ks < NF; ++ks) {
          Fn[2 * ks] = *(const float4*)(pb + ks * 128);
          Fn[2 * ks + 1] = *(const float4*)(pb + ks * 128 + 16);
        }
      } else {
        const char* pb = (const char*)Ain + (size_t)nt * (KD * 32) + lane * 16;
#pragma unroll
        for (int ks = 0; ks < NF; ++ks) An[ks] = *(const bf16x8*)(pb + ks * 1024);
      }
    }
    if constexpr (AF32) {  // convert current raw f32 -> bf16 fragments
#pragma unroll
      for (int ks = 0; ks < NF; ++ks) {
        float4 f0 = Fc[2 * ks], f1 = Fc[2 * ks + 1];
        uint4 u;
        u.x = f2bf(f0.x) | (f2bf(f0.y) << 16);
        u.y = f2bf(f0.z) | (f2bf(f0.w) << 16);
        u.z = f2bf(f1.x) | (f2bf(f1.y) << 16);
        u.w = f2bf(f1.z) | (f2bf(f1.w) << 16);
        Ac[ks] = *(bf16x8*)&u;
      }
    }
    // compute
    f32x4 acc[NJ];
#pragma unroll
    for (int j = 0; j < NJ; ++j) acc[j] = f32x4{0.f, 0.f, 0.f, 0.f};
#pragma unroll
    for (int ks = 0; ks < NF; ++ks) {
      int c = ks * 4 + hi;
#pragma unroll
      for (int j = 0; j < NJ; ++j) {
        int o = j * 16 + cl;
        bf16x8 wf = *(const bf16x8*)((const char*)sW + o * ROWB + ((c ^ (o & 15)) << 4));
        acc[j] = __builtin_amdgcn_mfma_f32_16x16x32_bf16(Ac[ks], wf, acc[j], 0, 0, 0);
      }
    }
    // store (C/D layout: col=lane&15, row=(lane>>4)*4+reg)
#pragma unroll
    for (int j = 0; j < NJ; ++j) {
      int col = j * 16 + cl;
#pragma unroll
      for (int reg = 0; reg < 4; ++reg) {
        int row = t * 16 + hi * 4 + reg;
        if (row < NN) {
          float v = acc[j][reg] + bv[j];
          if (RELU) v = fmaxf(v, 0.f);
          out[(size_t)row * OUTD + col] = (ushort)f2bf(v);
        }
      }
    }
    // ping-pong
    if (pf) {
      if constexpr (AF32) {
#pragma unroll
        for (int q = 0; q < 2 * NF; ++q) Fc[q] = Fn[q];
      } else {
#pragma unroll
        for (int ks = 0; ks < NF; ++ks) Ac[ks] = An[ks];
      }
    }
  }
}

// ---------------- layer-1 epilogue: h1 = relu(agg(Y1) + Z1 + b1) ----------------
// YZ rows are [Y(128bf16) | Z(128bf16)] = 512B. 16 lanes per node gather the Y half
// of neighbors (uint4/lane), add own Z + bias, relu, write row-major h1 [NN][128]bf16.
#define ACC8(q)                      \
  do {                               \
    acc[0] += bflo(q.x); acc[1] += bfhi(q.x); \
    acc[2] += bflo(q.y); acc[3] += bfhi(q.y); \
    acc[4] += bflo(q.z); acc[5] += bfhi(q.z); \
    acc[6] += bflo(q.w); acc[7] += bfhi(q.w); \
  } while (0)

__global__ __launch_bounds__(256) void k_agg_relu(const ushort* __restrict__ YZ,
                                                  const int* __restrict__ offsets,
                                                  const int* __restrict__ csr,
                                                  const float* __restrict__ bias,
                                                  ushort* __restrict__ h1) {
  int tid = threadIdx.x;
  int sg = tid >> 4, fl = tid & 15;
  int n = blockIdx.x * 16 + sg;
  if (n >= NN) return;
  int o0 = offsets[n], o1 = offsets[n + 1];
  const uint4* X4 = (const uint4*)YZ;  // row = 32 uint4: [0,16)=Y, [16,32)=Z
  float acc[8];
#pragma unroll
  for (int k = 0; k < 8; ++k) acc[k] = 0.f;
  int j = o0;
  if (j + 3 < o1) {
    uint4 q0 = X4[(size_t)csr[j] * 32 + fl];
    uint4 q1 = X4[(size_t)csr[j + 1] * 32 + fl];
    uint4 q2 = X4[(size_t)csr[j + 2] * 32 + fl];
    uint4 q3 = X4[(size_t)csr[j + 3] * 32 + fl];
    j += 4;
    while (j + 3 < o1) {
      uint4 p0 = X4[(size_t)csr[j] * 32 + fl];
      uint4 p1 = X4[(size_t)csr[j + 1] * 32 + fl];
      uint4 p2 = X4[(size_t)csr[j + 2] * 32 + fl];
      uint4 p3 = X4[(size_t)csr[j + 3] * 32 + fl];
      j += 4;
      ACC8(q0); ACC8(q1); ACC8(q2); ACC8(q3);
      q0 = p0; q1 = p1; q2 = p2; q3 = p3;
    }
    ACC8(q0); ACC8(q1); ACC8(q2); ACC8(q3);
  }
  for (; j < o1; ++j) {
    uint4 q = X4[(size_t)csr[j] * 32 + fl];
    ACC8(q);
  }
  uint4 zown = X4[(size_t)n * 32 + 16 + fl];
  float z[8] = {bflo(zown.x), bfhi(zown.x), bflo(zown.y), bfhi(zown.y),
                bflo(zown.z), bfhi(zown.z), bflo(zown.w), bfhi(zown.w)};
  const float4* b4 = (const float4*)bias;
  float4 bb0 = b4[fl * 2], bb1 = b4[fl * 2 + 1];
  float r[8];
  r[0] = fmaxf(acc[0] + z[0] + bb0.x, 0.f);
  r[1] = fmaxf(acc[1] + z[1] + bb0.y, 0.f);
  r[2] = fmaxf(acc[2] + z[2] + bb0.z, 0.f);
  r[3] = fmaxf(acc[3] + z[3] + bb0.w, 0.f);
  r[4] = fmaxf(acc[4] + z[4] + bb1.x, 0.f);
  r[5] = fmaxf(acc[5] + z[5] + bb1.y, 0.f);
  r[6] = fmaxf(acc[6] + z[6] + bb1.z, 0.f);
  r[7] = fmaxf(acc[7] + z[7] + bb1.w, 0.f);
  uint4 o;
  o.x = f2bf(r[0]) | (f2bf(r[1]) << 16);
  o.y = f2bf(r[2]) | (f2bf(r[3]) << 16);
  o.z = f2bf(r[4]) | (f2bf(r[5]) << 16);
  o.w = f2bf(r[6]) | (f2bf(r[7]) << 16);
  ((uint4*)h1)[(size_t)n * 16 + fl] = o;
}

// ------- layer-2 aggregation + root concat into K=256 GEMM panels -------
// ag[n] = [sum_{j in N(n)} h1_j | h1_n], panel layout, zero-padded to NPAD.
__global__ __launch_bounds__(256) void k_aggcat(const ushort* __restrict__ X,
                                                const int* __restrict__ offsets,
                                                const int* __restrict__ csr,
                                                ushort* __restrict__ ag) {
  int tid = threadIdx.x;
  int sg = tid >> 4, fl = tid & 15;
  int n = blockIdx.x * 16 + sg;
  uint4* AG = (uint4*)ag;
  size_t ob = (size_t)(n >> 4) * 512 + (size_t)fl * 16 + (n & 15);
  if (n >= NN) {
    uint4 z = make_uint4(0u, 0u, 0u, 0u);
    AG[ob] = z;
    AG[ob + 256] = z;
    return;
  }
  int o0 = offsets[n], o1 = offsets[n + 1];
  const uint4* X4 = (const uint4*)X;
  float acc[8];
#pragma unroll
  for (int k = 0; k < 8; ++k) acc[k] = 0.f;
  int j = o0;
  if (j + 3 < o1) {
    uint4 q0 = X4[(size_t)csr[j] * 16 + fl];
    uint4 q1 = X4[(size_t)csr[j + 1] * 16 + fl];
    uint4 q2 = X4[(size_t)csr[j + 2] * 16 + fl];
    uint4 q3 = X4[(size_t)csr[j + 3] * 16 + fl];
    j += 4;
    while (j + 3 < o1) {
      uint4 p0 = X4[(size_t)csr[j] * 16 + fl];
      uint4 p1 = X4[(size_t)csr[j + 1] * 16 + fl];
      uint4 p2 = X4[(size_t)csr[j + 2] * 16 + fl];
      uint4 p3 = X4[(size_t)csr[j + 3] * 16 + fl];
      j += 4;
      ACC8(q0); ACC8(q1); ACC8(q2); ACC8(q3);
      q0 = p0; q1 = p1; q2 = p2; q3 = p3;
    }
    ACC8(q0); ACC8(q1); ACC8(q2); ACC8(q3);
  }
  for (; j < o1; ++j) {
    uint4 q = X4[(size_t)csr[j] * 16 + fl];
    ACC8(q);
  }
  uint4 own = X4[(size_t)n * 16 + fl];
  uint4 o;
  o.x = f2bf(acc[0]) | (f2bf(acc[1]) << 16);
  o.y = f2bf(acc[2]) | (f2bf(acc[3]) << 16);
  o.z = f2bf(acc[4]) | (f2bf(acc[5]) << 16);
  o.w = f2bf(acc[6]) | (f2bf(acc[7]) << 16);
  AG[ob] = o;
  AG[ob + 256] = own;
}

// ---------------- layer 3 MFMA: y3b = h2@Wrel3 (bf16); z(d_out) = h2@Wroot3 + b3 ----------------
__global__ __launch_bounds__(512) void k_l3m(const ushort* __restrict__ h2,
                                             const ushort* __restrict__ Wt3,
                                             const float* __restrict__ bias,
                                             ushort* __restrict__ y3b, float* __restrict__ z) {
  int tid = threadIdx.x;
  int lane = tid & 63, wid = tid >> 6;
  int cl = lane & 15, hi = lane >> 4;
  size_t row0 = ((size_t)blockIdx.x * 8 + wid) * 16;
  bf16x8 b0[8], b1[8];
#pragma unroll
  for (int ks = 0; ks < 8; ++ks) {
    b0[ks] = *(const bf16x8*)(Wt3 + cl * 256 + ks * 32 + hi * 8);
    b1[ks] = *(const bf16x8*)(Wt3 + (16 + cl) * 256 + ks * 32 + hi * 8);
  }
  const ushort* arow = h2 + (row0 + cl) * 256 + hi * 8;
  f32x4 acc0 = {0.f, 0.f, 0.f, 0.f}, acc1 = {0.f, 0.f, 0.f, 0.f};
#pragma unroll
  for (int ks = 0; ks < 8; ++ks) {
    bf16x8 a = *(const bf16x8*)(arow + ks * 32);
    acc0 = __builtin_amdgcn_mfma_f32_16x16x32_bf16(a, b0[ks], acc0, 0, 0, 0);
    acc1 = __builtin_amdgcn_mfma_f32_16x16x32_bf16(a, b1[ks], acc1, 0, 0, 0);
  }
  float bv = bias[cl];
#pragma unroll
  for (int reg = 0; reg < 4; ++reg) {
    size_t row = row0 + hi * 4 + reg;
    if (row < NN) {
      y3b[row * 16 + cl] = (ushort)f2bf(acc0[reg]);
      z[row * 16 + cl] = acc1[reg] + bv;
    }
  }
}

// ---------------- fused: out = log_softmax(z + segsum(y3b[src])) ----------------
__global__ void k_agg16lsm(const int* __restrict__ offsets, const int* __restrict__ csr,
                           const ushort* __restrict__ y3b, float* __restrict__ out) {
  int t = blockIdx.x * 256 + threadIdx.x;  // (node, uint-pair) : 8 lanes per node
  if (t >= NN * 8) return;
  int n = t >> 3, g = t & 7;
  int o0 = offsets[n], o1 = offsets[n + 1];
  float a0 = 0.f, a1 = 0.f;
  const uint* Y = (const uint*)y3b;
  for (int j = o0; j < o1; ++j) {
    uint u = Y[(size_t)csr[j] * 8 + g];
    a0 += bflo(u); a1 += bfhi(u);
  }
  float v0 = out[n * 16 + g * 2] + a0;
  float v1 = out[n * 16 + g * 2 + 1] + a1;
  float m = fmaxf(v0, v1);
#pragma unroll
  for (int mask = 1; mask < 8; mask <<= 1) m = fmaxf(m, __shfl_xor(m, mask));
  float s = __expf(v0 - m) + __expf(v1 - m);
#pragma unroll
  for (int mask = 1; mask < 8; mask <<= 1) s += __shfl_xor(s, mask);
  float ls = __logf(s);
  out[n * 16 + g * 2] = v0 - m - ls;
  out[n * 16 + g * 2 + 1] = v1 - m - ls;
}

extern "C" void kernel_launch(void* const* d_in, const int* in_sizes, int n_in,
                              void* d_out, int out_size, void* d_ws, size_t ws_size,
                              hipStream_t stream) {
  const float* x = (const float*)d_in[0];
  const int* ei = (const int*)d_in[1];  // [2][NE]: row0=src, row1=dst
  const float* Wrel1 = (const float*)d_in[2];
  const float* Wroot1 = (const float*)d_in[3];
  const float* b1 = (const float*)d_in[4];
  const float* Wrel2 = (const float*)d_in[5];
  const float* Wroot2 = (const float*)d_in[6];
  const float* b2 = (const float*)d_in[7];
  const float* Wrel3 = (const float*)d_in[8];
  const float* Wroot3 = (const float*)d_in[9];
  const float* b3 = (const float*)d_in[10];
  float* out = (float*)d_out;

  char* ws = (char*)d_ws;
  size_t off = 0;
  auto alloc = [&](size_t bytes) {
    void* p = ws + off;
    off += (bytes + 255) / 256 * 256;
    return p;
  };
  int* deg = (int*)alloc((size_t)NN * 4);
  int* offsets = (int*)alloc((size_t)(NN + 1) * 4);
  int* cursor = (int*)alloc((size_t)NN * 4);
  int* bsum = (int*)alloc(128 * 4);
  int* bpre = (int*)alloc(128 * 4);
  int* csr = (int*)alloc((size_t)NE * 4);
  ushort* yz = (ushort*)alloc((size_t)NN * 256 * 2);    // [Y1|Z1] row-major 512B rows
  ushort* h1 = (ushort*)alloc((size_t)NN * 128 * 2);    // row-major 256B rows
  ushort* ag2 = (ushort*)alloc((size_t)NPAD * 256 * 2); // K=256 panels
  ushort* h2 = (ushort*)alloc((size_t)NPAD * 256 * 2);  // row-major 512B rows
  ushort* y3b = (ushort*)alloc((size_t)NN * 16 * 2);
  ushort* wt = (ushort*)alloc((size_t)106496 * 2);
  ushort *Wst1 = wt, *Wst2 = wt + 32768;
  ushort* Wt3 = wt + 98304;

  const int* src = ei;
  const int* dst = ei + NE;

  k_cvt_w<<<(106496 + 255) / 256, 256, 0, stream>>>(Wrel1, Wroot1, Wrel2, Wroot2, Wrel3,
                                                    Wroot3, wt);
  // layer 1 dense part (no CSR dep): [Y1|Z1] = X @ [Wrel1|Wroot1], X read as f32
  k_gemm_stream<128, 256, 1, 0, 0><<<256, 512, 0, stream>>>(x, Wst1, nullptr, yz, NN / 16);

  // CSR build (XCD-partitioned hist + scatter)
  hipMemsetAsync(deg, 0, (size_t)NN * 4, stream);
  int nchunk = (NE + 2047) / 2048;  // 391
  k_hist<<<8 * nchunk, 256, 0, stream>>>(dst, deg);
  int NB = (NN + 1023) / 1024;  // 98
  k_scan_partial<<<NB, 256, 0, stream>>>(deg, bsum, NN);
  k_scan_bsums<<<1, 128, 0, stream>>>(bsum, bpre, offsets, NB, NN);
  k_scan_final<<<NB, 256, 0, stream>>>(deg, bpre, offsets, cursor, NN);
  k_scatter<<<8 * nchunk, 256, 0, stream>>>(src, dst, cursor, csr);

  // h1 = relu(agg(Y1) + Z1 + b1)   [linearity: agg(X)@Wr = agg(X@Wr)]
  k_agg_relu<<<NN / 16, 256, 0, stream>>>(yz, offsets, csr, b1, h1);
  // layer 2: ag2 = [agg(h1)|h1] panels ; h2 = relu(ag2 @ [Wr2;Wo2] + b2)
  k_aggcat<<<NPAD / 16, 256, 0, stream>>>(h1, offsets, csr, ag2);
  k_gemm_stream<256, 256, 0, 1, 1><<<256, 512, 0, stream>>>(ag2, Wst2, b2, h2, NPAD / 16);
  // layer 3
  k_l3m<<<NPAD / 128, 512, 0, stream>>>(h2, Wt3, b3, y3b, out);
  k_agg16lsm<<<(NN * 8 + 255) / 256, 256, 0, stream>>>(offsets, csr, y3b, out);
}

// Round 4
// 273.677 us; speedup vs baseline: 2.0671x; 2.0671x over previous
//
#include <hip/hip_runtime.h>

#define NN 100000
#define NE 800000
#define NPAD 100096  // 782*128 = 391*256, so GEMM row tiles never read OOB
#define OCT 12544    // 8*12544 = 100352 >= NN ; dst/OCT = XCD octant

typedef __attribute__((ext_vector_type(8))) __bf16 bf16x8;
typedef __attribute__((ext_vector_type(4))) float f32x4;

__device__ __forceinline__ uint f2bf(float f) {  // f32 -> bf16 bits (RNE), low 16
  uint u = __float_as_uint(f);
  return (u + 0x7fffu + ((u >> 16) & 1u)) >> 16;
}
__device__ __forceinline__ float bflo(uint u) { return __uint_as_float(u << 16); }
__device__ __forceinline__ float bfhi(uint u) { return __uint_as_float(u & 0xffff0000u); }

// ---------------- fused prep: cvt_x + cvt_w + hist in ONE dispatch ----------------
// blocks [0,12512): x f32->bf16 ; [12512,12928): weight transpose+convert ;
// [12928,16056): XCD-partitioned degree histogram (offset 12928 % 8 == 0 keeps
// the blockIdx%8 -> XCD round-robin alignment for the octant-partitioned atomics).
__global__ __launch_bounds__(256) void k_prep(
    const float* __restrict__ x, ushort* __restrict__ xb,
    const float* __restrict__ Wr1, const float* __restrict__ Wo1,
    const float* __restrict__ Wr2, const float* __restrict__ Wo2,
    const float* __restrict__ Wr3, const float* __restrict__ Wo3,
    ushort* __restrict__ wt, const int* __restrict__ dst, int* __restrict__ deg) {
  int b = blockIdx.x;
  if (b < 12512) {  // ---- cvt_x: 12512*256 = NPAD*32 groups of 4 floats
    int i = b * 256 + threadIdx.x;
    int row = i >> 5;
    float4 v = (row < NN) ? ((const float4*)x)[i] : make_float4(0.f, 0.f, 0.f, 0.f);
    uint2 o;
    o.x = f2bf(v.x) | (f2bf(v.y) << 16);
    o.y = f2bf(v.z) | (f2bf(v.w) << 16);
    ((uint2*)xb)[i] = o;
  } else if (b < 12928) {  // ---- cvt_w: 416*256 = 106496 elements
    int idx = (b - 12512) * 256 + threadIdx.x;
    float v;
    if (idx < 98304) {
      const float* W;
      int base, OUT;
      if (idx < 16384) { W = Wr1; base = 0; OUT = 128; }
      else if (idx < 32768) { W = Wo1; base = 16384; OUT = 128; }
      else if (idx < 65536) { W = Wr2; base = 32768; OUT = 256; }
      else { W = Wo2; base = 65536; OUT = 256; }
      int li = idx - base;
      int o = li >> 7, k = li & 127;
      v = W[(size_t)k * OUT + o];
    } else {
      int li = idx - 98304;  // [32][256]: o<16 -> Wrel3 col o ; o>=16 -> Wroot3 col o-16
      int o = li >> 8, k = li & 255;
      v = (o < 16) ? Wr3[(size_t)k * 16 + o] : Wo3[(size_t)k * 16 + (o - 16)];
    }
    wt[idx] = (ushort)f2bf(v);
  } else {  // ---- hist: 3128 = 8*391 blocks
    int hb = b - 12928;
    int xcd = hb & 7, chunk = hb >> 3;
    int e0 = chunk * 2048 + threadIdx.x;
#pragma unroll
    for (int i = 0; i < 8; ++i) {
      int e = e0 + i * 256;
      if (e < NE) {
        int d = dst[e];
        if (d / OCT == xcd) atomicAdd(&deg[d], 1);
      }
    }
  }
}

// ---------------- scans ----------------
__global__ void k_scan_partial(const int* __restrict__ deg, int* __restrict__ bsum, int N) {
  __shared__ int s[256];
  int b = blockIdx.x, t = threadIdx.x;
  int base = b * 1024 + t * 4;
  int v = 0;
#pragma unroll
  for (int i = 0; i < 4; ++i) { int idx = base + i; if (idx < N) v += deg[idx]; }
  s[t] = v; __syncthreads();
  for (int o = 128; o > 0; o >>= 1) { if (t < o) s[t] += s[t + o]; __syncthreads(); }
  if (t == 0) bsum[b] = s[0];
}

__global__ void k_scan_bsums(const int* __restrict__ bsum, int* __restrict__ bpre,
                             int* __restrict__ offsets, int NB, int N) {
  __shared__ int s[128];
  int t = threadIdx.x;
  int v = (t < NB) ? bsum[t] : 0;
  s[t] = v; __syncthreads();
  for (int o = 1; o < 128; o <<= 1) {
    int add = (t >= o) ? s[t - o] : 0;
    __syncthreads();
    s[t] += add;
    __syncthreads();
  }
  if (t < NB) bpre[t] = s[t] - v;
  if (t == NB - 1) offsets[N] = s[t];
}

__global__ void k_scan_final(const int* __restrict__ deg, const int* __restrict__ bpre,
                             int* __restrict__ offsets, int* __restrict__ cursor, int N) {
  __shared__ int s[256];
  int b = blockIdx.x, t = threadIdx.x;
  int base = b * 1024 + t * 4;
  int v[4];
#pragma unroll
  for (int i = 0; i < 4; ++i) { int idx = base + i; v[i] = (idx < N) ? deg[idx] : 0; }
  int tsum = v[0] + v[1] + v[2] + v[3];
  s[t] = tsum; __syncthreads();
  for (int o = 1; o < 256; o <<= 1) {
    int add = (t >= o) ? s[t - o] : 0;
    __syncthreads();
    s[t] += add;
    __syncthreads();
  }
  int run = s[t] - tsum + bpre[b];
#pragma unroll
  for (int i = 0; i < 4; ++i) {
    int idx = base + i;
    if (idx < N) { offsets[idx] = run; cursor[idx] = run; }
    run += v[i];
  }
}

__global__ __launch_bounds__(256) void k_scatter(const int* __restrict__ src,
                                                 const int* __restrict__ dst,
                                                 int* __restrict__ cursor,
                                                 int* __restrict__ csr_src) {
  int xcd = blockIdx.x & 7, chunk = blockIdx.x >> 3;
  int e0 = chunk * 2048 + threadIdx.x;
#pragma unroll
  for (int i = 0; i < 8; ++i) {
    int e = e0 + i * 256;
    if (e < NE) {
      int d = dst[e];
      if (d / OCT == xcd) {
        int pos = atomicAdd(&cursor[d], 1);
        csr_src[pos] = src[e];
      }
    }
  }
}

// ------- aggregation (128-dim bf16): one 16-lane subgroup per node, pipelined 4-batches ----
#define ACC8(q)                      \
  do {                               \
    acc[0] += bflo(q.x); acc[1] += bfhi(q.x); \
    acc[2] += bflo(q.y); acc[3] += bfhi(q.y); \
    acc[4] += bflo(q.z); acc[5] += bfhi(q.z); \
    acc[6] += bflo(q.w); acc[7] += bfhi(q.w); \
  } while (0)

__global__ __launch_bounds__(256) void k_aggbf(const ushort* __restrict__ X,
                                               const int* __restrict__ offsets,
                                               const int* __restrict__ csr,
                                               ushort* __restrict__ out) {
  int tid = threadIdx.x;
  int sg = tid >> 4, fl = tid & 15;
  int n = blockIdx.x * 16 + sg;
  if (n >= NN) return;
  int o0 = offsets[n], o1 = offsets[n + 1];
  const uint4* X4 = (const uint4*)X;
  float acc[8];
#pragma unroll
  for (int k = 0; k < 8; ++k) acc[k] = 0.f;
  int j = o0;
  if (j + 3 < o1) {
    uint4 q0 = X4[(size_t)csr[j] * 16 + fl];
    uint4 q1 = X4[(size_t)csr[j + 1] * 16 + fl];
    uint4 q2 = X4[(size_t)csr[j + 2] * 16 + fl];
    uint4 q3 = X4[(size_t)csr[j + 3] * 16 + fl];
    j += 4;
    while (j + 3 < o1) {
      uint4 p0 = X4[(size_t)csr[j] * 16 + fl];
      uint4 p1 = X4[(size_t)csr[j + 1] * 16 + fl];
      uint4 p2 = X4[(size_t)csr[j + 2] * 16 + fl];
      uint4 p3 = X4[(size_t)csr[j + 3] * 16 + fl];
      j += 4;
      ACC8(q0); ACC8(q1); ACC8(q2); ACC8(q3);
      q0 = p0; q1 = p1; q2 = p2; q3 = p3;
    }
    ACC8(q0); ACC8(q1); ACC8(q2); ACC8(q3);
  }
  for (; j < o1; ++j) {
    uint4 q = X4[(size_t)csr[j] * 16 + fl];
    ACC8(q);
  }
  uint4 o;
  o.x = f2bf(acc[0]) | (f2bf(acc[1]) << 16);
  o.y = f2bf(acc[2]) | (f2bf(acc[3]) << 16);
  o.z = f2bf(acc[4]) | (f2bf(acc[5]) << 16);
  o.w = f2bf(acc[6]) | (f2bf(acc[7]) << 16);
  ((uint4*)out)[(size_t)n * 16 + fl] = o;
}

// ---------------- MFMA dual GEMM: out = act(Aagg@Wrel + Aroot@Wroot + b), K=128 ----------------
// Round-0 structure (best measured: 48us/dispatch): W-only LDS (64 KB -> 2 blocks/CU);
// A streamed global->reg, depth-2 ks pipeline, first two K-steps issued BEFORE the
// W-stage barrier. Changes vs round 0:
//  - swizzle widened (row&7)->(row&15): verified (r1) SQ_LDS_BANK_CONFLICT 1.6M -> 0.
//  - NCH=2: 1-D grid with pair decode so both c-halves of one r-tile land on the
//    SAME XCD back-to-back -> second half's 128KB A-read hits that XCD's L2.
__device__ __forceinline__ bf16x8 ldfrag(const ushort* base, int row, int kb) {
  int off = (row << 8) + (kb ^ ((row & 15) << 4));
  return *(const bf16x8*)((const char*)base + off);
}

template <int RELU, int NCH>
__global__ __launch_bounds__(512, 4) void k_gemm_mfma(
    const ushort* __restrict__ Aagg, const ushort* __restrict__ Aroot,
    const ushort* __restrict__ Wrelt, const ushort* __restrict__ Wroott,
    const float* __restrict__ bias, ushort* __restrict__ out, int OUT) {
  __shared__ ushort sWr[128 * 128];
  __shared__ ushort sWo[128 * 128];
  int tid = threadIdx.x;
  int pr, half;
  if (NCH == 2) {  // pair decode: blocks p and p+8 share pr -> same XCD, adjacent in queue
    int p = blockIdx.x;
    half = (p >> 3) & 1;
    pr = (p >> 4) * 8 + (p & 7);
    if (pr >= NPAD / 256) return;
  } else {
    pr = blockIdx.x;
    half = 0;
  }
  int r0 = pr * 256;
  int c0 = half * 128;

  int lane = tid & 63, wid = tid >> 6;
  int cl = lane & 15, hi = lane >> 4;
  const ushort* pa = Aagg + (size_t)(r0 + wid * 32 + cl) * 128 + hi * 8;
  const ushort* pr_ = Aroot + (size_t)(r0 + wid * 32 + cl) * 128 + hi * 8;

  // issue ks=0,1 A-loads first (overlap W-stage drain)
  bf16x8 A0[2], A1[2], R0[2], R1[2];
  A0[0] = *(const bf16x8*)(pa);
  A0[1] = *(const bf16x8*)(pa + 32);
  A1[0] = *(const bf16x8*)(pa + 2048);
  A1[1] = *(const bf16x8*)(pa + 2048 + 32);
  R0[0] = *(const bf16x8*)(pr_);
  R0[1] = *(const bf16x8*)(pr_ + 32);
  R1[0] = *(const bf16x8*)(pr_ + 2048);
  R1[1] = *(const bf16x8*)(pr_ + 2048 + 32);

  const char* gw = (const char*)(Wrelt + (size_t)c0 * 128);
  const char* gu = (const char*)(Wroott + (size_t)c0 * 128);
#pragma unroll
  for (int i = 0; i < 4; ++i) {
    int L = (tid + i * 512) << 4;    // linear LDS byte in 32KB
    int row = L >> 8;
    int gb = L ^ ((row & 15) << 4);  // pre-swizzled global source (involution in-row)
    __builtin_amdgcn_global_load_lds((const __attribute__((address_space(1))) void*)(gw + gb),
                                     (__attribute__((address_space(3))) void*)((char*)sWr + L), 16, 0, 0);
    __builtin_amdgcn_global_load_lds((const __attribute__((address_space(1))) void*)(gu + gb),
                                     (__attribute__((address_space(3))) void*)((char*)sWo + L), 16, 0, 0);
  }
  __syncthreads();

  f32x4 zero = {0.f, 0.f, 0.f, 0.f};
  f32x4 acc0[8], acc1[8];
#pragma unroll
  for (int j = 0; j < 8; ++j) { acc0[j] = zero; acc1[j] = zero; }

#pragma unroll
  for (int ks = 0; ks < 4; ++ks) {
    const int p = ks & 1;
    int kb = ks * 64 + hi * 16;
#pragma unroll
    for (int j = 0; j < 8; ++j) {
      bf16x8 wf = ldfrag(sWr, j * 16 + cl, kb);
      bf16x8 uf = ldfrag(sWo, j * 16 + cl, kb);
      acc0[j] = __builtin_amdgcn_mfma_f32_16x16x32_bf16(A0[p], wf, acc0[j], 0, 0, 0);
      acc1[j] = __builtin_amdgcn_mfma_f32_16x16x32_bf16(A1[p], wf, acc1[j], 0, 0, 0);
      acc0[j] = __builtin_amdgcn_mfma_f32_16x16x32_bf16(R0[p], uf, acc0[j], 0, 0, 0);
      acc1[j] = __builtin_amdgcn_mfma_f32_16x16x32_bf16(R1[p], uf, acc1[j], 0, 0, 0);
    }
    if (ks < 2) {  // reload slot p with K-step ks+2
      A0[p] = *(const bf16x8*)(pa + (ks + 2) * 32);
      A1[p] = *(const bf16x8*)(pa + 2048 + (ks + 2) * 32);
      R0[p] = *(const bf16x8*)(pr_ + (ks + 2) * 32);
      R1[p] = *(const bf16x8*)(pr_ + 2048 + (ks + 2) * 32);
    }
  }

  // epilogue: C/D layout col=lane&15, row=(lane>>4)*4+reg (m89)
#pragma unroll
  for (int j = 0; j < 8; ++j) {
    int col = c0 + j * 16 + cl;
    float bv = bias[col];
#pragma unroll
    for (int i = 0; i < 2; ++i) {
#pragma unroll
      for (int reg = 0; reg < 4; ++reg) {
        int row = r0 + wid * 32 + i * 16 + hi * 4 + reg;
        if (row < NN) {
          float v = (i ? acc1[j][reg] : acc0[j][reg]) + bv;
          if (RELU) v = fmaxf(v, 0.f);
          out[(size_t)row * OUT + col] = (ushort)f2bf(v);
        }
      }
    }
  }
}

// ---------------- layer 3 MFMA: y3b = h2@Wrel3 (bf16); z(d_out) = h2@Wroot3 + b3 ----------------
__global__ __launch_bounds__(512) void k_l3m(const ushort* __restrict__ h2,
                                             const ushort* __restrict__ Wt3,
                                             const float* __restrict__ bias,
                                             ushort* __restrict__ y3b, float* __restrict__ z) {
  int tid = threadIdx.x;
  int lane = tid & 63, wid = tid >> 6;
  int cl = lane & 15, hi = lane >> 4;
  size_t row0 = ((size_t)blockIdx.x * 8 + wid) * 16;
  bf16x8 b0[8], b1[8];
#pragma unroll
  for (int ks = 0; ks < 8; ++ks) {
    b0[ks] = *(const bf16x8*)(Wt3 + cl * 256 + ks * 32 + hi * 8);
    b1[ks] = *(const bf16x8*)(Wt3 + (16 + cl) * 256 + ks * 32 + hi * 8);
  }
  const ushort* arow = h2 + (row0 + cl) * 256 + hi * 8;
  f32x4 acc0 = {0.f, 0.f, 0.f, 0.f}, acc1 = {0.f, 0.f, 0.f, 0.f};
#pragma unroll
  for (int ks = 0; ks < 8; ++ks) {
    bf16x8 a = *(const bf16x8*)(arow + ks * 32);
    acc0 = __builtin_amdgcn_mfma_f32_16x16x32_bf16(a, b0[ks], acc0, 0, 0, 0);
    acc1 = __builtin_amdgcn_mfma_f32_16x16x32_bf16(a, b1[ks], acc1, 0, 0, 0);
  }
  float bv = bias[cl];
#pragma unroll
  for (int reg = 0; reg < 4; ++reg) {
    size_t row = row0 + hi * 4 + reg;
    if (row < NN) {
      y3b[row * 16 + cl] = (ushort)f2bf(acc0[reg]);
      z[row * 16 + cl] = acc1[reg] + bv;
    }
  }
}

// ---------------- fused: out = log_softmax(z + segsum(y3b[src])) ----------------
__global__ void k_agg16lsm(const int* __restrict__ offsets, const int* __restrict__ csr,
                           const ushort* __restrict__ y3b, float* __restrict__ out) {
  int t = blockIdx.x * 256 + threadIdx.x;  // (node, uint-pair) : 8 lanes per node
  if (t >= NN * 8) return;
  int n = t >> 3, g = t & 7;
  int o0 = offsets[n], o1 = offsets[n + 1];
  float a0 = 0.f, a1 = 0.f;
  const uint* Y = (const uint*)y3b;
  for (int j = o0; j < o1; ++j) {
    uint u = Y[(size_t)csr[j] * 8 + g];
    a0 += bflo(u); a1 += bfhi(u);
  }
  float v0 = out[n * 16 + g * 2] + a0;
  float v1 = out[n * 16 + g * 2 + 1] + a1;
  float m = fmaxf(v0, v1);
#pragma unroll
  for (int mask = 1; mask < 8; mask <<= 1) m = fmaxf(m, __shfl_xor(m, mask));
  float s = __expf(v0 - m) + __expf(v1 - m);
#pragma unroll
  for (int mask = 1; mask < 8; mask <<= 1) s += __shfl_xor(s, mask);
  float ls = __logf(s);
  out[n * 16 + g * 2] = v0 - m - ls;
  out[n * 16 + g * 2 + 1] = v1 - m - ls;
}

extern "C" void kernel_launch(void* const* d_in, const int* in_sizes, int n_in,
                              void* d_out, int out_size, void* d_ws, size_t ws_size,
                              hipStream_t stream) {
  const float* x = (const float*)d_in[0];
  const int* ei = (const int*)d_in[1];  // [2][NE]: row0=src, row1=dst
  const float* Wrel1 = (const float*)d_in[2];
  const float* Wroot1 = (const float*)d_in[3];
  const float* b1 = (const float*)d_in[4];
  const float* Wrel2 = (const float*)d_in[5];
  const float* Wroot2 = (const float*)d_in[6];
  const float* b2 = (const float*)d_in[7];
  const float* Wrel3 = (const float*)d_in[8];
  const float* Wroot3 = (const float*)d_in[9];
  const float* b3 = (const float*)d_in[10];
  float* out = (float*)d_out;

  char* ws = (char*)d_ws;
  size_t off = 0;
  auto alloc = [&](size_t bytes) {
    void* p = ws + off;
    off += (bytes + 255) / 256 * 256;
    return p;
  };
  int* deg = (int*)alloc((size_t)NN * 4);
  int* offsets = (int*)alloc((size_t)(NN + 1) * 4);
  int* cursor = (int*)alloc((size_t)NN * 4);
  int* bsum = (int*)alloc(128 * 4);
  int* bpre = (int*)alloc(128 * 4);
  int* csr = (int*)alloc((size_t)NE * 4);
  ushort* xb = (ushort*)alloc((size_t)NPAD * 128 * 2);
  ushort* aggb = (ushort*)alloc((size_t)NPAD * 128 * 2);
  ushort* h1b = (ushort*)alloc((size_t)NPAD * 128 * 2);
  ushort* h2b = (ushort*)alloc((size_t)NPAD * 256 * 2);
  ushort* y3b = (ushort*)alloc((size_t)NN * 16 * 2);
  ushort* wt = (ushort*)alloc((size_t)106496 * 2);
  ushort *Wr1t = wt, *Wo1t = wt + 16384, *Wr2t = wt + 32768, *Wo2t = wt + 65536;
  ushort* Wt3 = wt + 98304;

  const int* src = ei;
  const int* dst = ei + NE;

  // fused prep: cvt_x + cvt_w + hist (deg memset must precede)
  hipMemsetAsync(deg, 0, (size_t)NN * 4, stream);
  k_prep<<<16056, 256, 0, stream>>>(x, xb, Wrel1, Wroot1, Wrel2, Wroot2, Wrel3, Wroot3,
                                    wt, dst, deg);

  // CSR build
  int NB = (NN + 1023) / 1024;  // 98
  k_scan_partial<<<NB, 256, 0, stream>>>(deg, bsum, NN);
  k_scan_bsums<<<1, 128, 0, stream>>>(bsum, bpre, offsets, NB, NN);
  k_scan_final<<<NB, 256, 0, stream>>>(deg, bpre, offsets, cursor, NN);
  int nchunk = (NE + 2047) / 2048;  // 391
  k_scatter<<<8 * nchunk, 256, 0, stream>>>(src, dst, cursor, csr);

  // layer 1: h1 = relu(agg(x)@Wr1 + x@Wo1 + b1)
  k_aggbf<<<(NN + 15) / 16, 256, 0, stream>>>(xb, offsets, csr, aggb);
  k_gemm_mfma<1, 1><<<NPAD / 256, 512, 0, stream>>>(aggb, xb, Wr1t, Wo1t, b1, h1b, 128);
  // layer 2: h2 = relu(agg(h1)@Wr2 + h1@Wo2 + b2)
  k_aggbf<<<(NN + 15) / 16, 256, 0, stream>>>(h1b, offsets, csr, aggb);
  k_gemm_mfma<1, 2><<<784, 512, 0, stream>>>(aggb, h1b, Wr2t, Wo2t, b2, h2b, 256);
  // layer 3
  k_l3m<<<NPAD / 128, 512, 0, stream>>>(h2b, Wt3, b3, y3b, out);
  k_agg16lsm<<<(NN * 8 + 255) / 256, 256, 0, stream>>>(offsets, csr, y3b, out);
}

// Round 5
// 251.976 us; speedup vs baseline: 2.2451x; 1.0861x over previous
//
#include <hip/hip_runtime.h>

#define NN 100000
#define NE 800000
#define NPAD 100096  // 782*128 = 391*256, so GEMM row tiles never read OOB
#define OCT 12544    // 8*12544 = 100352 >= NN ; dst/OCT = XCD octant

typedef __attribute__((ext_vector_type(8))) __bf16 bf16x8;
typedef __attribute__((ext_vector_type(4))) float f32x4;

__device__ __forceinline__ uint f2bf(float f) {  // f32 -> bf16 bits (RNE), low 16
  uint u = __float_as_uint(f);
  return (u + 0x7fffu + ((u >> 16) & 1u)) >> 16;
}
__device__ __forceinline__ float bflo(uint u) { return __uint_as_float(u << 16); }
__device__ __forceinline__ float bfhi(uint u) { return __uint_as_float(u & 0xffff0000u); }

// C-storage permutation (per 128-col half): stored col p = cl*8 + j holds original
// col c(p) = (p&7)*16 + (p>>3). Lets each lane write its 8 per-row acc values as ONE
// contiguous uint4 -> wave stores are full 64B sectors (kills the 1.8-2.8x HBM write
// amplification of the scalar-ushort epilogue). h1b/h2b are internal; aggbf is
// elementwise over cols (permutation-transparent); W2/W3 K-rows permuted in cvt_w.

// ---------------- fused prep: cvt_x + cvt_w + hist in ONE dispatch ----------------
// blocks [0,12512): x f32->bf16 ; [12512,12928): weight transpose+convert ;
// [12928,16056): XCD-partitioned degree histogram (offset 12928 % 8 == 0 keeps
// the blockIdx%8 -> XCD round-robin alignment for the octant-partitioned atomics).
__global__ __launch_bounds__(256) void k_prep(
    const float* __restrict__ x, ushort* __restrict__ xb,
    const float* __restrict__ Wr1, const float* __restrict__ Wo1,
    const float* __restrict__ Wr2, const float* __restrict__ Wo2,
    const float* __restrict__ Wr3, const float* __restrict__ Wo3,
    ushort* __restrict__ wt, const int* __restrict__ dst, int* __restrict__ deg) {
  int b = blockIdx.x;
  if (b < 12512) {  // ---- cvt_x: 12512*256 = NPAD*32 groups of 4 floats
    int i = b * 256 + threadIdx.x;
    int row = i >> 5;
    float4 v = (row < NN) ? ((const float4*)x)[i] : make_float4(0.f, 0.f, 0.f, 0.f);
    uint2 o;
    o.x = f2bf(v.x) | (f2bf(v.y) << 16);
    o.y = f2bf(v.z) | (f2bf(v.w) << 16);
    ((uint2*)xb)[i] = o;
  } else if (b < 12928) {  // ---- cvt_w: 416*256 = 106496 elements
    int idx = (b - 12512) * 256 + threadIdx.x;
    float v;
    if (idx < 98304) {
      const float* W;
      int base, OUT, perm;
      if (idx < 16384) { W = Wr1; base = 0; OUT = 128; perm = 0; }
      else if (idx < 32768) { W = Wo1; base = 16384; OUT = 128; perm = 0; }
      else if (idx < 65536) { W = Wr2; base = 32768; OUT = 256; perm = 1; }
      else { W = Wo2; base = 65536; OUT = 256; perm = 1; }
      int li = idx - base;
      int o = li >> 7, k = li & 127;
      if (perm) k = (k & 7) * 16 + (k >> 3);  // h1b stored-col -> original col
      v = W[(size_t)k * OUT + o];
    } else {
      int li = idx - 98304;  // Wt3 [32][256]: o<16 -> Wrel3 col o ; o>=16 -> Wroot3
      int o = li >> 8, ks = li & 255;
      int kk = ks & 127;  // h2b stored-col -> original col (per 128-half)
      int k = (ks & 128) + (kk & 7) * 16 + (kk >> 3);
      v = (o < 16) ? Wr3[(size_t)k * 16 + o] : Wo3[(size_t)k * 16 + (o - 16)];
    }
    wt[idx] = (ushort)f2bf(v);
  } else {  // ---- hist: 3128 = 8*391 blocks
    int hb = b - 12928;
    int xcd = hb & 7, chunk = hb >> 3;
    int e0 = chunk * 2048 + threadIdx.x;
#pragma unroll
    for (int i = 0; i < 8; ++i) {
      int e = e0 + i * 256;
      if (e < NE) {
        int d = dst[e];
        if (d / OCT == xcd) atomicAdd(&deg[d], 1);
      }
    }
  }
}

// ---------------- scans ----------------
__global__ void k_scan_partial(const int* __restrict__ deg, int* __restrict__ bsum, int N) {
  __shared__ int s[256];
  int b = blockIdx.x, t = threadIdx.x;
  int base = b * 1024 + t * 4;
  int v = 0;
#pragma unroll
  for (int i = 0; i < 4; ++i) { int idx = base + i; if (idx < N) v += deg[idx]; }
  s[t] = v; __syncthreads();
  for (int o = 128; o > 0; o >>= 1) { if (t < o) s[t] += s[t + o]; __syncthreads(); }
  if (t == 0) bsum[b] = s[0];
}

__global__ void k_scan_bsums(const int* __restrict__ bsum, int* __restrict__ bpre,
                             int* __restrict__ offsets, int NB, int N) {
  __shared__ int s[128];
  int t = threadIdx.x;
  int v = (t < NB) ? bsum[t] : 0;
  s[t] = v; __syncthreads();
  for (int o = 1; o < 128; o <<= 1) {
    int add = (t >= o) ? s[t - o] : 0;
    __syncthreads();
    s[t] += add;
    __syncthreads();
  }
  if (t < NB) bpre[t] = s[t] - v;
  if (t == NB - 1) offsets[N] = s[t];
}

__global__ void k_scan_final(const int* __restrict__ deg, const int* __restrict__ bpre,
                             int* __restrict__ offsets, int* __restrict__ cursor, int N) {
  __shared__ int s[256];
  int b = blockIdx.x, t = threadIdx.x;
  int base = b * 1024 + t * 4;
  int v[4];
#pragma unroll
  for (int i = 0; i < 4; ++i) { int idx = base + i; v[i] = (idx < N) ? deg[idx] : 0; }
  int tsum = v[0] + v[1] + v[2] + v[3];
  s[t] = tsum; __syncthreads();
  for (int o = 1; o < 256; o <<= 1) {
    int add = (t >= o) ? s[t - o] : 0;
    __syncthreads();
    s[t] += add;
    __syncthreads();
  }
  int run = s[t] - tsum + bpre[b];
#pragma unroll
  for (int i = 0; i < 4; ++i) {
    int idx = base + i;
    if (idx < N) { offsets[idx] = run; cursor[idx] = run; }
    run += v[i];
  }
}

__global__ __launch_bounds__(256) void k_scatter(const int* __restrict__ src,
                                                 const int* __restrict__ dst,
                                                 int* __restrict__ cursor,
                                                 int* __restrict__ csr_src) {
  int xcd = blockIdx.x & 7, chunk = blockIdx.x >> 3;
  int e0 = chunk * 2048 + threadIdx.x;
#pragma unroll
  for (int i = 0; i < 8; ++i) {
    int e = e0 + i * 256;
    if (e < NE) {
      int d = dst[e];
      if (d / OCT == xcd) {
        int pos = atomicAdd(&cursor[d], 1);
        csr_src[pos] = src[e];
      }
    }
  }
}

// ------- aggregation (128-dim bf16): one 16-lane subgroup per node, pipelined 4-batches ----
#define ACC8(q)                      \
  do {                               \
    acc[0] += bflo(q.x); acc[1] += bfhi(q.x); \
    acc[2] += bflo(q.y); acc[3] += bfhi(q.y); \
    acc[4] += bflo(q.z); acc[5] += bfhi(q.z); \
    acc[6] += bflo(q.w); acc[7] += bfhi(q.w); \
  } while (0)

__global__ __launch_bounds__(256) void k_aggbf(const ushort* __restrict__ X,
                                               const int* __restrict__ offsets,
                                               const int* __restrict__ csr,
                                               ushort* __restrict__ out) {
  int tid = threadIdx.x;
  int sg = tid >> 4, fl = tid & 15;
  int n = blockIdx.x * 16 + sg;
  if (n >= NN) return;
  int o0 = offsets[n], o1 = offsets[n + 1];
  const uint4* X4 = (const uint4*)X;
  float acc[8];
#pragma unroll
  for (int k = 0; k < 8; ++k) acc[k] = 0.f;
  int j = o0;
  if (j + 3 < o1) {
    uint4 q0 = X4[(size_t)csr[j] * 16 + fl];
    uint4 q1 = X4[(size_t)csr[j + 1] * 16 + fl];
    uint4 q2 = X4[(size_t)csr[j + 2] * 16 + fl];
    uint4 q3 = X4[(size_t)csr[j + 3] * 16 + fl];
    j += 4;
    while (j + 3 < o1) {
      uint4 p0 = X4[(size_t)csr[j] * 16 + fl];
      uint4 p1 = X4[(size_t)csr[j + 1] * 16 + fl];
      uint4 p2 = X4[(size_t)csr[j + 2] * 16 + fl];
      uint4 p3 = X4[(size_t)csr[j + 3] * 16 + fl];
      j += 4;
      ACC8(q0); ACC8(q1); ACC8(q2); ACC8(q3);
      q0 = p0; q1 = p1; q2 = p2; q3 = p3;
    }
    ACC8(q0); ACC8(q1); ACC8(q2); ACC8(q3);
  }
  for (; j < o1; ++j) {
    uint4 q = X4[(size_t)csr[j] * 16 + fl];
    ACC8(q);
  }
  uint4 o;
  o.x = f2bf(acc[0]) | (f2bf(acc[1]) << 16);
  o.y = f2bf(acc[2]) | (f2bf(acc[3]) << 16);
  o.z = f2bf(acc[4]) | (f2bf(acc[5]) << 16);
  o.w = f2bf(acc[6]) | (f2bf(acc[7]) << 16);
  ((uint4*)out)[(size_t)n * 16 + fl] = o;
}

// ---------------- MFMA dual GEMM: out = act(Aagg@Wrel + Aroot@Wroot + b), K=128 ----------------
// Round-0 structure (best measured): W-only LDS (64 KB -> 2 blocks/CU); A streamed
// global->reg, depth-2 ks pipeline, first two K-steps issued BEFORE the W-stage barrier.
//  - swizzle (row&15): verified r1, SQ_LDS_BANK_CONFLICT = 0.
//  - NCH=2 pair decode (r4): halves of one r-tile on same XCD; FETCH halved (verified).
//  - NEW r5: permuted-column uint4 epilogue (see top comment) — full-sector stores.
__device__ __forceinline__ bf16x8 ldfrag(const ushort* base, int row, int kb) {
  int off = (row << 8) + (kb ^ ((row & 15) << 4));
  return *(const bf16x8*)((const char*)base + off);
}

template <int RELU, int NCH>
__global__ __launch_bounds__(512, 4) void k_gemm_mfma(
    const ushort* __restrict__ Aagg, const ushort* __restrict__ Aroot,
    const ushort* __restrict__ Wrelt, const ushort* __restrict__ Wroott,
    const float* __restrict__ bias, ushort* __restrict__ out, int OUT) {
  __shared__ ushort sWr[128 * 128];
  __shared__ ushort sWo[128 * 128];
  int tid = threadIdx.x;
  int pr, half;
  if (NCH == 2) {  // pair decode: blocks p and p+8 share pr -> same XCD, adjacent in queue
    int p = blockIdx.x;
    half = (p >> 3) & 1;
    pr = (p >> 4) * 8 + (p & 7);
    if (pr >= NPAD / 256) return;
  } else {
    pr = blockIdx.x;
    half = 0;
  }
  int r0 = pr * 256;
  int c0 = half * 128;

  int lane = tid & 63, wid = tid >> 6;
  int cl = lane & 15, hi = lane >> 4;
  const ushort* pa = Aagg + (size_t)(r0 + wid * 32 + cl) * 128 + hi * 8;
  const ushort* pr_ = Aroot + (size_t)(r0 + wid * 32 + cl) * 128 + hi * 8;

  // issue ks=0,1 A-loads first (overlap W-stage drain)
  bf16x8 A0[2], A1[2], R0[2], R1[2];
  A0[0] = *(const bf16x8*)(pa);
  A0[1] = *(const bf16x8*)(pa + 32);
  A1[0] = *(const bf16x8*)(pa + 2048);
  A1[1] = *(const bf16x8*)(pa + 2048 + 32);
  R0[0] = *(const bf16x8*)(pr_);
  R0[1] = *(const bf16x8*)(pr_ + 32);
  R1[0] = *(const bf16x8*)(pr_ + 2048);
  R1[1] = *(const bf16x8*)(pr_ + 2048 + 32);

  const char* gw = (const char*)(Wrelt + (size_t)c0 * 128);
  const char* gu = (const char*)(Wroott + (size_t)c0 * 128);
#pragma unroll
  for (int i = 0; i < 4; ++i) {
    int L = (tid + i * 512) << 4;    // linear LDS byte in 32KB
    int row = L >> 8;
    int gb = L ^ ((row & 15) << 4);  // pre-swizzled global source (involution in-row)
    __builtin_amdgcn_global_load_lds((const __attribute__((address_space(1))) void*)(gw + gb),
                                     (__attribute__((address_space(3))) void*)((char*)sWr + L), 16, 0, 0);
    __builtin_amdgcn_global_load_lds((const __attribute__((address_space(1))) void*)(gu + gb),
                                     (__attribute__((address_space(3))) void*)((char*)sWo + L), 16, 0, 0);
  }
  __syncthreads();

  f32x4 zero = {0.f, 0.f, 0.f, 0.f};
  f32x4 acc0[8], acc1[8];
#pragma unroll
  for (int j = 0; j < 8; ++j) { acc0[j] = zero; acc1[j] = zero; }

#pragma unroll
  for (int ks = 0; ks < 4; ++ks) {
    const int p = ks & 1;
    int kb = ks * 64 + hi * 16;
#pragma unroll
    for (int j = 0; j < 8; ++j) {
      bf16x8 wf = ldfrag(sWr, j * 16 + cl, kb);
      bf16x8 uf = ldfrag(sWo, j * 16 + cl, kb);
      acc0[j] = __builtin_amdgcn_mfma_f32_16x16x32_bf16(A0[p], wf, acc0[j], 0, 0, 0);
      acc1[j] = __builtin_amdgcn_mfma_f32_16x16x32_bf16(A1[p], wf, acc1[j], 0, 0, 0);
      acc0[j] = __builtin_amdgcn_mfma_f32_16x16x32_bf16(R0[p], uf, acc0[j], 0, 0, 0);
      acc1[j] = __builtin_amdgcn_mfma_f32_16x16x32_bf16(R1[p], uf, acc1[j], 0, 0, 0);
    }
    if (ks < 2) {  // reload slot p with K-step ks+2
      A0[p] = *(const bf16x8*)(pa + (ks + 2) * 32);
      A1[p] = *(const bf16x8*)(pa + 2048 + (ks + 2) * 32);
      R0[p] = *(const bf16x8*)(pr_ + (ks + 2) * 32);
      R1[p] = *(const bf16x8*)(pr_ + 2048 + (ks + 2) * 32);
    }
  }

  // bias in ORIGINAL col space, per j (value for orig col c0 + j*16 + cl)
  float bv[8];
#pragma unroll
  for (int j = 0; j < 8; ++j) bv[j] = bias[c0 + j * 16 + cl];

  // permuted-column epilogue: lane packs its 8 per-row values -> one uint4 at
  // stored cols [c0 + cl*8, c0 + cl*8 + 8). Wave-store = 4 rows x 256B full sectors.
#pragma unroll
  for (int i = 0; i < 2; ++i) {
#pragma unroll
    for (int reg = 0; reg < 4; ++reg) {
      int row = r0 + wid * 32 + i * 16 + hi * 4 + reg;
      if (row < NN) {
        float a[8];
#pragma unroll
        for (int j = 0; j < 8; ++j) {
          float v = (i ? acc1[j][reg] : acc0[j][reg]) + bv[j];
          if (RELU) v = fmaxf(v, 0.f);
          a[j] = v;
        }
        uint4 u;
        u.x = f2bf(a[0]) | (f2bf(a[1]) << 16);
        u.y = f2bf(a[2]) | (f2bf(a[3]) << 16);
        u.z = f2bf(a[4]) | (f2bf(a[5]) << 16);
        u.w = f2bf(a[6]) | (f2bf(a[7]) << 16);
        *(uint4*)(out + (size_t)row * OUT + c0 + cl * 8) = u;
      }
    }
  }
}

// ---------------- layer 3 MFMA: y3b = h2@Wrel3 (bf16); z(d_out) = h2@Wroot3 + b3 ----------------
// h2b is in permuted col space; Wt3's K-rows were permuted to match in cvt_w.
__global__ __launch_bounds__(512) void k_l3m(const ushort* __restrict__ h2,
                                             const ushort* __restrict__ Wt3,
                                             const float* __restrict__ bias,
                                             ushort* __restrict__ y3b, float* __restrict__ z) {
  int tid = threadIdx.x;
  int lane = tid & 63, wid = tid >> 6;
  int cl = lane & 15, hi = lane >> 4;
  size_t row0 = ((size_t)blockIdx.x * 8 + wid) * 16;
  bf16x8 b0[8], b1[8];
#pragma unroll
  for (int ks = 0; ks < 8; ++ks) {
    b0[ks] = *(const bf16x8*)(Wt3 + cl * 256 + ks * 32 + hi * 8);
    b1[ks] = *(const bf16x8*)(Wt3 + (16 + cl) * 256 + ks * 32 + hi * 8);
  }
  const ushort* arow = h2 + (row0 + cl) * 256 + hi * 8;
  f32x4 acc0 = {0.f, 0.f, 0.f, 0.f}, acc1 = {0.f, 0.f, 0.f, 0.f};
#pragma unroll
  for (int ks = 0; ks < 8; ++ks) {
    bf16x8 a = *(const bf16x8*)(arow + ks * 32);
    acc0 = __builtin_amdgcn_mfma_f32_16x16x32_bf16(a, b0[ks], acc0, 0, 0, 0);
    acc1 = __builtin_amdgcn_mfma_f32_16x16x32_bf16(a, b1[ks], acc1, 0, 0, 0);
  }
  float bv = bias[cl];
#pragma unroll
  for (int reg = 0; reg < 4; ++reg) {
    size_t row = row0 + hi * 4 + reg;
    if (row < NN) {
      y3b[row * 16 + cl] = (ushort)f2bf(acc0[reg]);
      z[row * 16 + cl] = acc1[reg] + bv;
    }
  }
}

// ---------------- fused: out = log_softmax(z + segsum(y3b[src])) ----------------
__global__ void k_agg16lsm(const int* __restrict__ offsets, const int* __restrict__ csr,
                           const ushort* __restrict__ y3b, float* __restrict__ out) {
  int t = blockIdx.x * 256 + threadIdx.x;  // (node, uint-pair) : 8 lanes per node
  if (t >= NN * 8) return;
  int n = t >> 3, g = t & 7;
  int o0 = offsets[n], o1 = offsets[n + 1];
  float a0 = 0.f, a1 = 0.f;
  const uint* Y = (const uint*)y3b;
  for (int j = o0; j < o1; ++j) {
    uint u = Y[(size_t)csr[j] * 8 + g];
    a0 += bflo(u); a1 += bfhi(u);
  }
  float v0 = out[n * 16 + g * 2] + a0;
  float v1 = out[n * 16 + g * 2 + 1] + a1;
  float m = fmaxf(v0, v1);
#pragma unroll
  for (int mask = 1; mask < 8; mask <<= 1) m = fmaxf(m, __shfl_xor(m, mask));
  float s = __expf(v0 - m) + __expf(v1 - m);
#pragma unroll
  for (int mask = 1; mask < 8; mask <<= 1) s += __shfl_xor(s, mask);
  float ls = __logf(s);
  out[n * 16 + g * 2] = v0 - m - ls;
  out[n * 16 + g * 2 + 1] = v1 - m - ls;
}

extern "C" void kernel_launch(void* const* d_in, const int* in_sizes, int n_in,
                              void* d_out, int out_size, void* d_ws, size_t ws_size,
                              hipStream_t stream) {
  const float* x = (const float*)d_in[0];
  const int* ei = (const int*)d_in[1];  // [2][NE]: row0=src, row1=dst
  const float* Wrel1 = (const float*)d_in[2];
  const float* Wroot1 = (const float*)d_in[3];
  const float* b1 = (const float*)d_in[4];
  const float* Wrel2 = (const float*)d_in[5];
  const float* Wroot2 = (const float*)d_in[6];
  const float* b2 = (const float*)d_in[7];
  const float* Wrel3 = (const float*)d_in[8];
  const float* Wroot3 = (const float*)d_in[9];
  const float* b3 = (const float*)d_in[10];
  float* out = (float*)d_out;

  char* ws = (char*)d_ws;
  size_t off = 0;
  auto alloc = [&](size_t bytes) {
    void* p = ws + off;
    off += (bytes + 255) / 256 * 256;
    return p;
  };
  int* deg = (int*)alloc((size_t)NN * 4);
  int* offsets = (int*)alloc((size_t)(NN + 1) * 4);
  int* cursor = (int*)alloc((size_t)NN * 4);
  int* bsum = (int*)alloc(128 * 4);
  int* bpre = (int*)alloc(128 * 4);
  int* csr = (int*)alloc((size_t)NE * 4);
  ushort* xb = (ushort*)alloc((size_t)NPAD * 128 * 2);
  ushort* aggb = (ushort*)alloc((size_t)NPAD * 128 * 2);
  ushort* h1b = (ushort*)alloc((size_t)NPAD * 128 * 2);
  ushort* h2b = (ushort*)alloc((size_t)NPAD * 256 * 2);
  ushort* y3b = (ushort*)alloc((size_t)NN * 16 * 2);
  ushort* wt = (ushort*)alloc((size_t)106496 * 2);
  ushort *Wr1t = wt, *Wo1t = wt + 16384, *Wr2t = wt + 32768, *Wo2t = wt + 65536;
  ushort* Wt3 = wt + 98304;

  const int* src = ei;
  const int* dst = ei + NE;

  // fused prep: cvt_x + cvt_w + hist (deg memset must precede)
  hipMemsetAsync(deg, 0, (size_t)NN * 4, stream);
  k_prep<<<16056, 256, 0, stream>>>(x, xb, Wrel1, Wroot1, Wrel2, Wroot2, Wrel3, Wroot3,
                                    wt, dst, deg);

  // CSR build
  int NB = (NN + 1023) / 1024;  // 98
  k_scan_partial<<<NB, 256, 0, stream>>>(deg, bsum, NN);
  k_scan_bsums<<<1, 128, 0, stream>>>(bsum, bpre, offsets, NB, NN);
  k_scan_final<<<NB, 256, 0, stream>>>(deg, bpre, offsets, cursor, NN);
  int nchunk = (NE + 2047) / 2048;  // 391
  k_scatter<<<8 * nchunk, 256, 0, stream>>>(src, dst, cursor, csr);

  // layer 1: h1 = relu(agg(x)@Wr1 + x@Wo1 + b1)
  k_aggbf<<<(NN + 15) / 16, 256, 0, stream>>>(xb, offsets, csr, aggb);
  k_gemm_mfma<1, 1><<<NPAD / 256, 512, 0, stream>>>(aggb, xb, Wr1t, Wo1t, b1, h1b, 128);
  // layer 2: h2 = relu(agg(h1)@Wr2 + h1@Wo2 + b2)
  k_aggbf<<<(NN + 15) / 16, 256, 0, stream>>>(h1b, offsets, csr, aggb);
  k_gemm_mfma<1, 2><<<784, 512, 0, stream>>>(aggb, h1b, Wr2t, Wo2t, b2, h2b, 256);
  // layer 3
  k_l3m<<<NPAD / 128, 512, 0, stream>>>(h2b, Wt3, b3, y3b, out);
  k_agg16lsm<<<(NN * 8 + 255) / 256, 256, 0, stream>>>(offsets, csr, y3b, out);
}

// Round 6
// 242.858 us; speedup vs baseline: 2.3294x; 1.0375x over previous
//
#include <hip/hip_runtime.h>

#define NN 100000
#define NE 800000
#define NPAD 100096  // 782*128 = 391*256, so GEMM row tiles never read OOB
#define OCT 12544    // 8*12544 = 100352 >= NN ; dst/OCT = XCD octant

typedef __attribute__((ext_vector_type(8))) __bf16 bf16x8;
typedef __attribute__((ext_vector_type(4))) float f32x4;

__device__ __forceinline__ uint f2bf(float f) {  // f32 -> bf16 bits (RNE), low 16
  uint u = __float_as_uint(f);
  return (u + 0x7fffu + ((u >> 16) & 1u)) >> 16;
}
__device__ __forceinline__ float bflo(uint u) { return __uint_as_float(u << 16); }
__device__ __forceinline__ float bfhi(uint u) { return __uint_as_float(u & 0xffff0000u); }

__device__ __forceinline__ bf16x8 cvt8(float4 a, float4 b) {
  uint4 u;
  u.x = f2bf(a.x) | (f2bf(a.y) << 16);
  u.y = f2bf(a.z) | (f2bf(a.w) << 16);
  u.z = f2bf(b.x) | (f2bf(b.y) << 16);
  u.w = f2bf(b.z) | (f2bf(b.w) << 16);
  return *(bf16x8*)&u;
}

// C-storage permutation (per 128-col half): stored col p = cl*8 + j holds original
// col c(p) = (p&7)*16 + (p>>3). Full-sector uint4 epilogue stores (verified r5:
// killed the 1.8-2.8x HBM write amplification). h1b/h2b/yz internal; aggbf is
// permutation-transparent; W2/W3 K-rows permuted in cvt_w; b1 permuted in agg_relu.

__device__ __forceinline__ bf16x8 ldfrag(const ushort* base, int row, int kb) {
  int off = (row << 8) + (kb ^ ((row & 15) << 4));
  return *(const bf16x8*)((const char*)base + off);
}

// ---------------- fused dispatch 1: gemm1' + hist + cvt_w ----------------
// Layer-1 linearity: agg(X)@Wrel = agg(X@Wrel), so gemm1' = X_f32 @ [Wrel1|Wroot1]
// -> YZ (no CSR dependency, no cvt_x). The atomic-latency-bound hist rides in the
// same grid AFTER the gemm blocks so its latency hides under gemm BW/MFMA.
// blocks [0,784): gemm1' pair-decoded (pr,half) -> same-XCD halves share x reads in L2
// blocks [784,2352): octant hist (offset 784%8==0 keeps XCD alignment)
// blocks [2352,2496): cvt_w for W2/Wt3 (W1 staged from f32 inside gemm1')
__global__ __launch_bounds__(512, 4) void k_fuse1(
    const float* __restrict__ x, ushort* __restrict__ yz,
    const float* __restrict__ Wr1, const float* __restrict__ Wo1,
    const float* __restrict__ Wr2, const float* __restrict__ Wo2,
    const float* __restrict__ Wr3, const float* __restrict__ Wo3,
    ushort* __restrict__ wt, const int* __restrict__ dst, int* __restrict__ deg) {
  __shared__ ushort sW[128 * 128];  // 32 KB
  int b = blockIdx.x;
  int tid = threadIdx.x;

  if (b >= 2352) {  // ---- cvt_w: W2 (permuted K-rows) + Wt3; 144*512 = 73728
    int idx = 32768 + (b - 2352) * 512 + tid;
    float v;
    if (idx < 98304) {
      const float* W;
      int base;
      if (idx < 65536) { W = Wr2; base = 32768; }
      else { W = Wo2; base = 65536; }
      int li = idx - base;
      int o = li >> 7, k = li & 127;
      k = (k & 7) * 16 + (k >> 3);  // h1b stored-col -> original col
      v = W[(size_t)k * 256 + o];
    } else {
      int li = idx - 98304;  // Wt3 [32][256]
      int o = li >> 8, ks = li & 255;
      int kk = ks & 127;  // h2b stored-col -> original col (per 128-half)
      int k = (ks & 128) + (kk & 7) * 16 + (kk >> 3);
      v = (o < 16) ? Wr3[(size_t)k * 16 + o] : Wo3[(size_t)k * 16 + (o - 16)];
    }
    wt[idx] = (ushort)f2bf(v);
    return;
  }
  if (b >= 784) {  // ---- hist: 1568 = 8*196 blocks, 4096-edge chunks
    int hb = b - 784;
    int xcd = hb & 7, chunk = hb >> 3;
    int e0 = chunk * 4096 + tid;
#pragma unroll
    for (int i = 0; i < 8; ++i) {
      int e = e0 + i * 512;
      if (e < NE) {
        int d = dst[e];
        if (d / OCT == xcd) atomicAdd(&deg[d], 1);
      }
    }
    return;
  }

  // ---- gemm1': YZ[r, :] = [x@Wrel1 | x@Wroot1], rows 256/block, one 128-col half
  int half = (b >> 3) & 1;
  int pr = (b >> 4) * 8 + (b & 7);
  if (pr >= NPAD / 256) return;
  int r0 = pr * 256;
  int c0 = half * 128;

  int lane = tid & 63, wid = tid >> 6;
  int cl = lane & 15, hi = lane >> 4;
  int arow0 = r0 + wid * 32 + cl;
  int arow1 = arow0 + 16;
  const float* px0 = x + (size_t)(arow0 < NN ? arow0 : NN - 1) * 128;
  const float* px1 = x + (size_t)(arow1 < NN ? arow1 : NN - 1) * 128;

  // issue ks=0,1 A-loads first (f32, converted at use; r3-verified path)
  float4 F0[2][2], F1[2][2];
#pragma unroll
  for (int s = 0; s < 2; ++s) {
    F0[s][0] = *(const float4*)(px0 + s * 32 + hi * 8);
    F0[s][1] = *(const float4*)(px0 + s * 32 + hi * 8 + 4);
    F1[s][0] = *(const float4*)(px1 + s * 32 + hi * 8);
    F1[s][1] = *(const float4*)(px1 + s * 32 + hi * 8 + 4);
  }

  // stage this half's W (f32 source, [k][o] k-major) -> sW[o][k] bf16, XOR-swizzled
  {
    const float* Wsrc = half ? Wo1 : Wr1;
    int o = tid & 127;
    int kp = tid >> 7;  // 0..3
#pragma unroll
    for (int it = 0; it < 16; ++it) {
      int k0 = (it * 4 + kp) * 2;
      float w0 = Wsrc[(size_t)k0 * 128 + o];
      float w1 = Wsrc[(size_t)(k0 + 1) * 128 + o];
      uint u = f2bf(w0) | (f2bf(w1) << 16);
      int byte = (o << 8) + ((((k0 >> 3) << 4) ^ ((o & 15) << 4))) + (k0 & 7) * 2;
      *(uint*)((char*)sW + byte) = u;
    }
  }
  __syncthreads();

  f32x4 zero = {0.f, 0.f, 0.f, 0.f};
  f32x4 acc0[8], acc1[8];
#pragma unroll
  for (int j = 0; j < 8; ++j) { acc0[j] = zero; acc1[j] = zero; }

#pragma unroll
  for (int ks = 0; ks < 4; ++ks) {
    const int p = ks & 1;
    bf16x8 A0 = cvt8(F0[p][0], F0[p][1]);
    bf16x8 A1 = cvt8(F1[p][0], F1[p][1]);
    int kb = ks * 64 + hi * 16;
#pragma unroll
    for (int j = 0; j < 8; ++j) {
      bf16x8 wf = ldfrag(sW, j * 16 + cl, kb);
      acc0[j] = __builtin_amdgcn_mfma_f32_16x16x32_bf16(A0, wf, acc0[j], 0, 0, 0);
      acc1[j] = __builtin_amdgcn_mfma_f32_16x16x32_bf16(A1, wf, acc1[j], 0, 0, 0);
    }
    if (ks < 2) {
      F0[p][0] = *(const float4*)(px0 + (ks + 2) * 32 + hi * 8);
      F0[p][1] = *(const float4*)(px0 + (ks + 2) * 32 + hi * 8 + 4);
      F1[p][0] = *(const float4*)(px1 + (ks + 2) * 32 + hi * 8);
      F1[p][1] = *(const float4*)(px1 + (ks + 2) * 32 + hi * 8 + 4);
    }
  }

  // permuted-column uint4 epilogue (no bias/relu here; applied in agg_relu)
#pragma unroll
  for (int i = 0; i < 2; ++i) {
#pragma unroll
    for (int reg = 0; reg < 4; ++reg) {
      int row = r0 + wid * 32 + i * 16 + hi * 4 + reg;
      if (row < NN) {
        float a[8];
#pragma unroll
        for (int j = 0; j < 8; ++j) a[j] = i ? acc1[j][reg] : acc0[j][reg];
        uint4 u;
        u.x = f2bf(a[0]) | (f2bf(a[1]) << 16);
        u.y = f2bf(a[2]) | (f2bf(a[3]) << 16);
        u.z = f2bf(a[4]) | (f2bf(a[5]) << 16);
        u.w = f2bf(a[6]) | (f2bf(a[7]) << 16);
        *(uint4*)(yz + (size_t)row * 256 + c0 + cl * 8) = u;
      }
    }
  }
}

// ---------------- scans ----------------
__global__ void k_scan_partial(const int* __restrict__ deg, int* __restrict__ bsum, int N) {
  __shared__ int s[256];
  int b = blockIdx.x, t = threadIdx.x;
  int base = b * 1024 + t * 4;
  int v = 0;
#pragma unroll
  for (int i = 0; i < 4; ++i) { int idx = base + i; if (idx < N) v += deg[idx]; }
  s[t] = v; __syncthreads();
  for (int o = 128; o > 0; o >>= 1) { if (t < o) s[t] += s[t + o]; __syncthreads(); }
  if (t == 0) bsum[b] = s[0];
}

__global__ void k_scan_bsums(const int* __restrict__ bsum, int* __restrict__ bpre,
                             int* __restrict__ offsets, int NB, int N) {
  __shared__ int s[128];
  int t = threadIdx.x;
  int v = (t < NB) ? bsum[t] : 0;
  s[t] = v; __syncthreads();
  for (int o = 1; o < 128; o <<= 1) {
    int add = (t >= o) ? s[t - o] : 0;
    __syncthreads();
    s[t] += add;
    __syncthreads();
  }
  if (t < NB) bpre[t] = s[t] - v;
  if (t == NB - 1) offsets[N] = s[t];
}

__global__ void k_scan_final(const int* __restrict__ deg, const int* __restrict__ bpre,
                             int* __restrict__ offsets, int* __restrict__ cursor, int N) {
  __shared__ int s[256];
  int b = blockIdx.x, t = threadIdx.x;
  int base = b * 1024 + t * 4;
  int v[4];
#pragma unroll
  for (int i = 0; i < 4; ++i) { int idx = base + i; v[i] = (idx < N) ? deg[idx] : 0; }
  int tsum = v[0] + v[1] + v[2] + v[3];
  s[t] = tsum; __syncthreads();
  for (int o = 1; o < 256; o <<= 1) {
    int add = (t >= o) ? s[t - o] : 0;
    __syncthreads();
    s[t] += add;
    __syncthreads();
  }
  int run = s[t] - tsum + bpre[b];
#pragma unroll
  for (int i = 0; i < 4; ++i) {
    int idx = base + i;
    if (idx < N) { offsets[idx] = run; cursor[idx] = run; }
    run += v[i];
  }
}

__global__ __launch_bounds__(256) void k_scatter(const int* __restrict__ src,
                                                 const int* __restrict__ dst,
                                                 int* __restrict__ cursor,
                                                 int* __restrict__ csr_src) {
  int xcd = blockIdx.x & 7, chunk = blockIdx.x >> 3;
  int e0 = chunk * 2048 + threadIdx.x;
#pragma unroll
  for (int i = 0; i < 8; ++i) {
    int e = e0 + i * 256;
    if (e < NE) {
      int d = dst[e];
      if (d / OCT == xcd) {
        int pos = atomicAdd(&cursor[d], 1);
        csr_src[pos] = src[e];
      }
    }
  }
}

// ---------------- layer-1 epilogue: h1 = relu(agg(Y) + Z + b1) ----------------
// yz rows are [Y(128bf16) | Z(128bf16)] = 512B, permuted col storage. 16 lanes/node
// gather neighbor Y (uint4/lane), add own Z + permuted bias, relu, write h1 [NN][128].
#define ACC8(q)                      \
  do {                               \
    acc[0] += bflo(q.x); acc[1] += bfhi(q.x); \
    acc[2] += bflo(q.y); acc[3] += bfhi(q.y); \
    acc[4] += bflo(q.z); acc[5] += bfhi(q.z); \
    acc[6] += bflo(q.w); acc[7] += bfhi(q.w); \
  } while (0)

__global__ __launch_bounds__(256) void k_agg_relu(const ushort* __restrict__ YZ,
                                                  const int* __restrict__ offsets,
                                                  const int* __restrict__ csr,
                                                  const float* __restrict__ bias,
                                                  ushort* __restrict__ h1) {
  int tid = threadIdx.x;
  int sg = tid >> 4, fl = tid & 15;
  int n = blockIdx.x * 16 + sg;
  if (n >= NN) return;
  int o0 = offsets[n], o1 = offsets[n + 1];
  const uint4* X4 = (const uint4*)YZ;  // row = 32 uint4: [0,16)=Y, [16,32)=Z
  float acc[8];
#pragma unroll
  for (int k = 0; k < 8; ++k) acc[k] = 0.f;
  int j = o0;
  if (j + 3 < o1) {
    uint4 q0 = X4[(size_t)csr[j] * 32 + fl];
    uint4 q1 = X4[(size_t)csr[j + 1] * 32 + fl];
    uint4 q2 = X4[(size_t)csr[j + 2] * 32 + fl];
    uint4 q3 = X4[(size_t)csr[j + 3] * 32 + fl];
    j += 4;
    while (j + 3 < o1) {
      uint4 p0 = X4[(size_t)csr[j] * 32 + fl];
      uint4 p1 = X4[(size_t)csr[j + 1] * 32 + fl];
      uint4 p2 = X4[(size_t)csr[j + 2] * 32 + fl];
      uint4 p3 = X4[(size_t)csr[j + 3] * 32 + fl];
      j += 4;
      ACC8(q0); ACC8(q1); ACC8(q2); ACC8(q3);
      q0 = p0; q1 = p1; q2 = p2; q3 = p3;
    }
    ACC8(q0); ACC8(q1); ACC8(q2); ACC8(q3);
  }
  for (; j < o1; ++j) {
    uint4 q = X4[(size_t)csr[j] * 32 + fl];
    ACC8(q);
  }
  uint4 zown = X4[(size_t)n * 32 + 16 + fl];
  float z[8] = {bflo(zown.x), bfhi(zown.x), bflo(zown.y), bfhi(zown.y),
                bflo(zown.z), bfhi(zown.z), bflo(zown.w), bfhi(zown.w)};
  float r[8];
#pragma unroll
  for (int jj = 0; jj < 8; ++jj) {  // stored col fl*8+jj <-> orig col jj*16+fl
    r[jj] = fmaxf(acc[jj] + z[jj] + bias[jj * 16 + fl], 0.f);
  }
  uint4 o;
  o.x = f2bf(r[0]) | (f2bf(r[1]) << 16);
  o.y = f2bf(r[2]) | (f2bf(r[3]) << 16);
  o.z = f2bf(r[4]) | (f2bf(r[5]) << 16);
  o.w = f2bf(r[6]) | (f2bf(r[7]) << 16);
  ((uint4*)h1)[(size_t)n * 16 + fl] = o;
}

// ------- aggregation (128-dim bf16, permutation-transparent) -------
__global__ __launch_bounds__(256) void k_aggbf(const ushort* __restrict__ X,
                                               const int* __restrict__ offsets,
                                               const int* __restrict__ csr,
                                               ushort* __restrict__ out) {
  int tid = threadIdx.x;
  int sg = tid >> 4, fl = tid & 15;
  int n = blockIdx.x * 16 + sg;
  if (n >= NN) return;
  int o0 = offsets[n], o1 = offsets[n + 1];
  const uint4* X4 = (const uint4*)X;
  float acc[8];
#pragma unroll
  for (int k = 0; k < 8; ++k) acc[k] = 0.f;
  int j = o0;
  if (j + 3 < o1) {
    uint4 q0 = X4[(size_t)csr[j] * 16 + fl];
    uint4 q1 = X4[(size_t)csr[j + 1] * 16 + fl];
    uint4 q2 = X4[(size_t)csr[j + 2] * 16 + fl];
    uint4 q3 = X4[(size_t)csr[j + 3] * 16 + fl];
    j += 4;
    while (j + 3 < o1) {
      uint4 p0 = X4[(size_t)csr[j] * 16 + fl];
      uint4 p1 = X4[(size_t)csr[j + 1] * 16 + fl];
      uint4 p2 = X4[(size_t)csr[j + 2] * 16 + fl];
      uint4 p3 = X4[(size_t)csr[j + 3] * 16 + fl];
      j += 4;
      ACC8(q0); ACC8(q1); ACC8(q2); ACC8(q3);
      q0 = p0; q1 = p1; q2 = p2; q3 = p3;
    }
    ACC8(q0); ACC8(q1); ACC8(q2); ACC8(q3);
  }
  for (; j < o1; ++j) {
    uint4 q = X4[(size_t)csr[j] * 16 + fl];
    ACC8(q);
  }
  uint4 o;
  o.x = f2bf(acc[0]) | (f2bf(acc[1]) << 16);
  o.y = f2bf(acc[2]) | (f2bf(acc[3]) << 16);
  o.z = f2bf(acc[4]) | (f2bf(acc[5]) << 16);
  o.w = f2bf(acc[6]) | (f2bf(acc[7]) << 16);
  ((uint4*)out)[(size_t)n * 16 + fl] = o;
}

// ---------------- MFMA dual GEMM (layer 2): h2 = relu(agg@Wr2 + h1@Wo2 + b2) ----------------
// Round-0 structure + r1 swizzle + r4 XCD pair decode + r5 permuted uint4 epilogue.
template <int RELU, int NCH>
__global__ __launch_bounds__(512, 4) void k_gemm_mfma(
    const ushort* __restrict__ Aagg, const ushort* __restrict__ Aroot,
    const ushort* __restrict__ Wrelt, const ushort* __restrict__ Wroott,
    const float* __restrict__ bias, ushort* __restrict__ out, int OUT) {
  __shared__ ushort sWr[128 * 128];
  __shared__ ushort sWo[128 * 128];
  int tid = threadIdx.x;
  int pr, half;
  if (NCH == 2) {
    int p = blockIdx.x;
    half = (p >> 3) & 1;
    pr = (p >> 4) * 8 + (p & 7);
    if (pr >= NPAD / 256) return;
  } else {
    pr = blockIdx.x;
    half = 0;
  }
  int r0 = pr * 256;
  int c0 = half * 128;

  int lane = tid & 63, wid = tid >> 6;
  int cl = lane & 15, hi = lane >> 4;
  const ushort* pa = Aagg + (size_t)(r0 + wid * 32 + cl) * 128 + hi * 8;
  const ushort* pr_ = Aroot + (size_t)(r0 + wid * 32 + cl) * 128 + hi * 8;

  bf16x8 A0[2], A1[2], R0[2], R1[2];
  A0[0] = *(const bf16x8*)(pa);
  A0[1] = *(const bf16x8*)(pa + 32);
  A1[0] = *(const bf16x8*)(pa + 2048);
  A1[1] = *(const bf16x8*)(pa + 2048 + 32);
  R0[0] = *(const bf16x8*)(pr_);
  R0[1] = *(const bf16x8*)(pr_ + 32);
  R1[0] = *(const bf16x8*)(pr_ + 2048);
  R1[1] = *(const bf16x8*)(pr_ + 2048 + 32);

  const char* gw = (const char*)(Wrelt + (size_t)c0 * 128);
  const char* gu = (const char*)(Wroott + (size_t)c0 * 128);
#pragma unroll
  for (int i = 0; i < 4; ++i) {
    int L = (tid + i * 512) << 4;
    int row = L >> 8;
    int gb = L ^ ((row & 15) << 4);
    __builtin_amdgcn_global_load_lds((const __attribute__((address_space(1))) void*)(gw + gb),
                                     (__attribute__((address_space(3))) void*)((char*)sWr + L), 16, 0, 0);
    __builtin_amdgcn_global_load_lds((const __attribute__((address_space(1))) void*)(gu + gb),
                                     (__attribute__((address_space(3))) void*)((char*)sWo + L), 16, 0, 0);
  }
  __syncthreads();

  f32x4 zero = {0.f, 0.f, 0.f, 0.f};
  f32x4 acc0[8], acc1[8];
#pragma unroll
  for (int j = 0; j < 8; ++j) { acc0[j] = zero; acc1[j] = zero; }

#pragma unroll
  for (int ks = 0; ks < 4; ++ks) {
    const int p = ks & 1;
    int kb = ks * 64 + hi * 16;
#pragma unroll
    for (int j = 0; j < 8; ++j) {
      bf16x8 wf = ldfrag(sWr, j * 16 + cl, kb);
      bf16x8 uf = ldfrag(sWo, j * 16 + cl, kb);
      acc0[j] = __builtin_amdgcn_mfma_f32_16x16x32_bf16(A0[p], wf, acc0[j], 0, 0, 0);
      acc1[j] = __builtin_amdgcn_mfma_f32_16x16x32_bf16(A1[p], wf, acc1[j], 0, 0, 0);
      acc0[j] = __builtin_amdgcn_mfma_f32_16x16x32_bf16(R0[p], uf, acc0[j], 0, 0, 0);
      acc1[j] = __builtin_amdgcn_mfma_f32_16x16x32_bf16(R1[p], uf, acc1[j], 0, 0, 0);
    }
    if (ks < 2) {
      A0[p] = *(const bf16x8*)(pa + (ks + 2) * 32);
      A1[p] = *(const bf16x8*)(pa + 2048 + (ks + 2) * 32);
      R0[p] = *(const bf16x8*)(pr_ + (ks + 2) * 32);
      R1[p] = *(const bf16x8*)(pr_ + 2048 + (ks + 2) * 32);
    }
  }

  float bv[8];
#pragma unroll
  for (int j = 0; j < 8; ++j) bv[j] = bias[c0 + j * 16 + cl];

#pragma unroll
  for (int i = 0; i < 2; ++i) {
#pragma unroll
    for (int reg = 0; reg < 4; ++reg) {
      int row = r0 + wid * 32 + i * 16 + hi * 4 + reg;
      if (row < NN) {
        float a[8];
#pragma unroll
        for (int j = 0; j < 8; ++j) {
          float v = (i ? acc1[j][reg] : acc0[j][reg]) + bv[j];
          if (RELU) v = fmaxf(v, 0.f);
          a[j] = v;
        }
        uint4 u;
        u.x = f2bf(a[0]) | (f2bf(a[1]) << 16);
        u.y = f2bf(a[2]) | (f2bf(a[3]) << 16);
        u.z = f2bf(a[4]) | (f2bf(a[5]) << 16);
        u.w = f2bf(a[6]) | (f2bf(a[7]) << 16);
        *(uint4*)(out + (size_t)row * OUT + c0 + cl * 8) = u;
      }
    }
  }
}

// ---------------- layer 3 MFMA: y3b = h2@Wrel3 (bf16); z(d_out) = h2@Wroot3 + b3 ----------------
__global__ __launch_bounds__(512) void k_l3m(const ushort* __restrict__ h2,
                                             const ushort* __restrict__ Wt3,
                                             const float* __restrict__ bias,
                                             ushort* __restrict__ y3b, float* __restrict__ z) {
  int tid = threadIdx.x;
  int lane = tid & 63, wid = tid >> 6;
  int cl = lane & 15, hi = lane >> 4;
  size_t row0 = ((size_t)blockIdx.x * 8 + wid) * 16;
  bf16x8 b0[8], b1[8];
#pragma unroll
  for (int ks = 0; ks < 8; ++ks) {
    b0[ks] = *(const bf16x8*)(Wt3 + cl * 256 + ks * 32 + hi * 8);
    b1[ks] = *(const bf16x8*)(Wt3 + (16 + cl) * 256 + ks * 32 + hi * 8);
  }
  const ushort* arow = h2 + (row0 + cl) * 256 + hi * 8;
  f32x4 acc0 = {0.f, 0.f, 0.f, 0.f}, acc1 = {0.f, 0.f, 0.f, 0.f};
#pragma unroll
  for (int ks = 0; ks < 8; ++ks) {
    bf16x8 a = *(const bf16x8*)(arow + ks * 32);
    acc0 = __builtin_amdgcn_mfma_f32_16x16x32_bf16(a, b0[ks], acc0, 0, 0, 0);
    acc1 = __builtin_amdgcn_mfma_f32_16x16x32_bf16(a, b1[ks], acc1, 0, 0, 0);
  }
  float bv = bias[cl];
#pragma unroll
  for (int reg = 0; reg < 4; ++reg) {
    size_t row = row0 + hi * 4 + reg;
    if (row < NN) {
      y3b[row * 16 + cl] = (ushort)f2bf(acc0[reg]);
      z[row * 16 + cl] = acc1[reg] + bv;
    }
  }
}

// ---------------- fused: out = log_softmax(z + segsum(y3b[src])) ----------------
__global__ void k_agg16lsm(const int* __restrict__ offsets, const int* __restrict__ csr,
                           const ushort* __restrict__ y3b, float* __restrict__ out) {
  int t = blockIdx.x * 256 + threadIdx.x;  // (node, uint-pair) : 8 lanes per node
  if (t >= NN * 8) return;
  int n = t >> 3, g = t & 7;
  int o0 = offsets[n], o1 = offsets[n + 1];
  float a0 = 0.f, a1 = 0.f;
  const uint* Y = (const uint*)y3b;
  for (int j = o0; j < o1; ++j) {
    uint u = Y[(size_t)csr[j] * 8 + g];
    a0 += bflo(u); a1 += bfhi(u);
  }
  float v0 = out[n * 16 + g * 2] + a0;
  float v1 = out[n * 16 + g * 2 + 1] + a1;
  float m = fmaxf(v0, v1);
#pragma unroll
  for (int mask = 1; mask < 8; mask <<= 1) m = fmaxf(m, __shfl_xor(m, mask));
  float s = __expf(v0 - m) + __expf(v1 - m);
#pragma unroll
  for (int mask = 1; mask < 8; mask <<= 1) s += __shfl_xor(s, mask);
  float ls = __logf(s);
  out[n * 16 + g * 2] = v0 - m - ls;
  out[n * 16 + g * 2 + 1] = v1 - m - ls;
}

extern "C" void kernel_launch(void* const* d_in, const int* in_sizes, int n_in,
                              void* d_out, int out_size, void* d_ws, size_t ws_size,
                              hipStream_t stream) {
  const float* x = (const float*)d_in[0];
  const int* ei = (const int*)d_in[1];  // [2][NE]: row0=src, row1=dst
  const float* Wrel1 = (const float*)d_in[2];
  const float* Wroot1 = (const float*)d_in[3];
  const float* b1 = (const float*)d_in[4];
  const float* Wrel2 = (const float*)d_in[5];
  const float* Wroot2 = (const float*)d_in[6];
  const float* b2 = (const float*)d_in[7];
  const float* Wrel3 = (const float*)d_in[8];
  const float* Wroot3 = (const float*)d_in[9];
  const float* b3 = (const float*)d_in[10];
  float* out = (float*)d_out;

  char* ws = (char*)d_ws;
  size_t off = 0;
  auto alloc = [&](size_t bytes) {
    void* p = ws + off;
    off += (bytes + 255) / 256 * 256;
    return p;
  };
  int* deg = (int*)alloc((size_t)NN * 4);
  int* offsets = (int*)alloc((size_t)(NN + 1) * 4);
  int* cursor = (int*)alloc((size_t)NN * 4);
  int* bsum = (int*)alloc(128 * 4);
  int* bpre = (int*)alloc(128 * 4);
  int* csr = (int*)alloc((size_t)NE * 4);
  ushort* yz = (ushort*)alloc((size_t)NN * 256 * 2);     // [Y1|Z1], permuted cols
  ushort* aggb = (ushort*)alloc((size_t)NPAD * 128 * 2);
  ushort* h1b = (ushort*)alloc((size_t)NPAD * 128 * 2);
  ushort* h2b = (ushort*)alloc((size_t)NPAD * 256 * 2);
  ushort* y3b = (ushort*)alloc((size_t)NN * 16 * 2);
  ushort* wt = (ushort*)alloc((size_t)106496 * 2);
  ushort *Wr2t = wt + 32768, *Wo2t = wt + 65536;
  ushort* Wt3 = wt + 98304;

  const int* src = ei;
  const int* dst = ei + NE;

  // fused: gemm1' (X@[Wr1|Wo1] -> YZ) + hist + cvt_w(W2,Wt3)
  hipMemsetAsync(deg, 0, (size_t)NN * 4, stream);
  k_fuse1<<<2496, 512, 0, stream>>>(x, yz, Wrel1, Wroot1, Wrel2, Wroot2, Wrel3, Wroot3,
                                    wt, dst, deg);

  // CSR build
  int NB = (NN + 1023) / 1024;  // 98
  k_scan_partial<<<NB, 256, 0, stream>>>(deg, bsum, NN);
  k_scan_bsums<<<1, 128, 0, stream>>>(bsum, bpre, offsets, NB, NN);
  k_scan_final<<<NB, 256, 0, stream>>>(deg, bpre, offsets, cursor, NN);
  int nchunk = (NE + 2047) / 2048;  // 391
  k_scatter<<<8 * nchunk, 256, 0, stream>>>(src, dst, cursor, csr);

  // layer 1: h1 = relu(agg(Y1) + Z1 + b1)   [linearity: agg(X)@W = agg(X@W)]
  k_agg_relu<<<NN / 16, 256, 0, stream>>>(yz, offsets, csr, b1, h1b);
  // layer 2: h2 = relu(agg(h1)@Wr2 + h1@Wo2 + b2)
  k_aggbf<<<(NN + 15) / 16, 256, 0, stream>>>(h1b, offsets, csr, aggb);
  k_gemm_mfma<1, 2><<<784, 512, 0, stream>>>(aggb, h1b, Wr2t, Wo2t, b2, h2b, 256);
  // layer 3
  k_l3m<<<NPAD / 128, 512, 0, stream>>>(h2b, Wt3, b3, y3b, out);
  k_agg16lsm<<<(NN * 8 + 255) / 256, 256, 0, stream>>>(offsets, csr, y3b, out);
}

// Round 7
// 230.175 us; speedup vs baseline: 2.4577x; 1.0551x over previous
//
#include <hip/hip_runtime.h>

#define NN 100000
#define NE 800000
#define NPAD 100096  // 782*128 = 391*256
#define OCT 12544    // 8*12544 = 100352 >= NN ; dst/OCT = XCD octant

typedef __attribute__((ext_vector_type(8))) __bf16 bf16x8;
typedef __attribute__((ext_vector_type(4))) float f32x4;

__device__ __forceinline__ uint f2bf(float f) {  // f32 -> bf16 bits (RNE), low 16
  uint u = __float_as_uint(f);
  return (u + 0x7fffu + ((u >> 16) & 1u)) >> 16;
}
__device__ __forceinline__ float bflo(uint u) { return __uint_as_float(u << 16); }
__device__ __forceinline__ float bfhi(uint u) { return __uint_as_float(u & 0xffff0000u); }

__device__ __forceinline__ bf16x8 cvt8(float4 a, float4 b) {
  uint4 u;
  u.x = f2bf(a.x) | (f2bf(a.y) << 16);
  u.y = f2bf(a.z) | (f2bf(a.w) << 16);
  u.z = f2bf(b.x) | (f2bf(b.y) << 16);
  u.w = f2bf(b.z) | (f2bf(b.w) << 16);
  return *(bf16x8*)&u;
}

// Column-storage permutations for internal tensors (verified r5: full-sector uint4
// epilogues kill HBM write amplification):
//  - 128-col tensors (Y1/Z1/h1b/aggb): stored p = cl*8+j holds orig (p&7)*16+(p>>3).
//    W2 K-rows permuted to match in cvt_w.
//  - h2 tile (LDS-only now): stored p = cl*16+j holds orig (p&15)*16+(p>>4).
//    Wt3 K-rows permuted to match in cvt_w.

__device__ __forceinline__ bf16x8 ldfrag(const ushort* base, int row, int kb) {
  int off = (row << 8) + (kb ^ ((row & 15) << 4));
  return *(const bf16x8*)((const char*)base + off);
}

// ---------------- fused dispatch 1: gemm1' + hist + cvt_w ----------------
// Layer-1 linearity: agg(X)@Wrel = agg(X@Wrel) -> gemm1' = X_f32 @ [Wrel1|Wroot1].
// r6 verified: hist latency hides under gemm BW/MFMA in the same grid.
// r7: Y and Z go to SEPARATE arrays (halves the agg_relu gather footprint).
__global__ __launch_bounds__(512, 4) void k_fuse1(
    const float* __restrict__ x, ushort* __restrict__ Y1, ushort* __restrict__ Z1,
    const float* __restrict__ Wr1, const float* __restrict__ Wo1,
    const float* __restrict__ Wr2, const float* __restrict__ Wo2,
    const float* __restrict__ Wr3, const float* __restrict__ Wo3,
    ushort* __restrict__ wt, const int* __restrict__ dst, int* __restrict__ deg) {
  __shared__ ushort sW[128 * 128];  // 32 KB
  int b = blockIdx.x;
  int tid = threadIdx.x;

  if (b >= 2352) {  // ---- cvt_w: W2 (128-perm K) + Wt3 (256-perm K); 144*512
    int idx = 32768 + (b - 2352) * 512 + tid;
    float v;
    if (idx < 98304) {
      const float* W;
      int base;
      if (idx < 65536) { W = Wr2; base = 32768; }
      else { W = Wo2; base = 65536; }
      int li = idx - base;
      int o = li >> 7, k = li & 127;
      k = (k & 7) * 16 + (k >> 3);  // h1-space stored-col -> original col
      v = W[(size_t)k * 256 + o];
    } else {
      int li = idx - 98304;  // Wt3 [32][256]
      int o = li >> 8, p = li & 255;
      int k = (p & 15) * 16 + (p >> 4);  // h2-tile stored-col -> original col
      v = (o < 16) ? Wr3[(size_t)k * 16 + o] : Wo3[(size_t)k * 16 + (o - 16)];
    }
    wt[idx] = (ushort)f2bf(v);
    return;
  }
  if (b >= 784) {  // ---- hist: 1568 = 8*196 blocks, 4096-edge chunks
    int hb = b - 784;
    int xcd = hb & 7, chunk = hb >> 3;
    int e0 = chunk * 4096 + tid;
#pragma unroll
    for (int i = 0; i < 8; ++i) {
      int e = e0 + i * 512;
      if (e < NE) {
        int d = dst[e];
        if (d / OCT == xcd) atomicAdd(&deg[d], 1);
      }
    }
    return;
  }

  // ---- gemm1': 256 rows/block, one 128-col half; pair-decoded for same-XCD x reuse
  int half = (b >> 3) & 1;
  int pr = (b >> 4) * 8 + (b & 7);
  if (pr >= NPAD / 256) return;
  int r0 = pr * 256;

  int lane = tid & 63, wid = tid >> 6;
  int cl = lane & 15, hi = lane >> 4;
  int arow0 = r0 + wid * 32 + cl;
  int arow1 = arow0 + 16;
  const float* px0 = x + (size_t)(arow0 < NN ? arow0 : NN - 1) * 128;
  const float* px1 = x + (size_t)(arow1 < NN ? arow1 : NN - 1) * 128;

  float4 F0[2][2], F1[2][2];
#pragma unroll
  for (int s = 0; s < 2; ++s) {
    F0[s][0] = *(const float4*)(px0 + s * 32 + hi * 8);
    F0[s][1] = *(const float4*)(px0 + s * 32 + hi * 8 + 4);
    F1[s][0] = *(const float4*)(px1 + s * 32 + hi * 8);
    F1[s][1] = *(const float4*)(px1 + s * 32 + hi * 8 + 4);
  }

  {  // stage this half's W1 (f32 [k][o]) -> sW[o][k] bf16, XOR-swizzled
    const float* Wsrc = half ? Wo1 : Wr1;
    int o = tid & 127;
    int kp = tid >> 7;
#pragma unroll
    for (int it = 0; it < 16; ++it) {
      int k0 = (it * 4 + kp) * 2;
      float w0 = Wsrc[(size_t)k0 * 128 + o];
      float w1 = Wsrc[(size_t)(k0 + 1) * 128 + o];
      uint u = f2bf(w0) | (f2bf(w1) << 16);
      int byte = (o << 8) + ((((k0 >> 3) << 4) ^ ((o & 15) << 4))) + (k0 & 7) * 2;
      *(uint*)((char*)sW + byte) = u;
    }
  }
  __syncthreads();

  f32x4 zero = {0.f, 0.f, 0.f, 0.f};
  f32x4 acc0[8], acc1[8];
#pragma unroll
  for (int j = 0; j < 8; ++j) { acc0[j] = zero; acc1[j] = zero; }

#pragma unroll
  for (int ks = 0; ks < 4; ++ks) {
    const int p = ks & 1;
    bf16x8 A0 = cvt8(F0[p][0], F0[p][1]);
    bf16x8 A1 = cvt8(F1[p][0], F1[p][1]);
    int kb = ks * 64 + hi * 16;
#pragma unroll
    for (int j = 0; j < 8; ++j) {
      bf16x8 wf = ldfrag(sW, j * 16 + cl, kb);
      acc0[j] = __builtin_amdgcn_mfma_f32_16x16x32_bf16(A0, wf, acc0[j], 0, 0, 0);
      acc1[j] = __builtin_amdgcn_mfma_f32_16x16x32_bf16(A1, wf, acc1[j], 0, 0, 0);
    }
    if (ks < 2) {
      F0[p][0] = *(const float4*)(px0 + (ks + 2) * 32 + hi * 8);
      F0[p][1] = *(const float4*)(px0 + (ks + 2) * 32 + hi * 8 + 4);
      F1[p][0] = *(const float4*)(px1 + (ks + 2) * 32 + hi * 8);
      F1[p][1] = *(const float4*)(px1 + (ks + 2) * 32 + hi * 8 + 4);
    }
  }

  ushort* tgt = half ? Z1 : Y1;  // split arrays (r7)
#pragma unroll
  for (int i = 0; i < 2; ++i) {
#pragma unroll
    for (int reg = 0; reg < 4; ++reg) {
      int row = r0 + wid * 32 + i * 16 + hi * 4 + reg;
      if (row < NN) {
        float a[8];
#pragma unroll
        for (int j = 0; j < 8; ++j) a[j] = i ? acc1[j][reg] : acc0[j][reg];
        uint4 u;
        u.x = f2bf(a[0]) | (f2bf(a[1]) << 16);
        u.y = f2bf(a[2]) | (f2bf(a[3]) << 16);
        u.z = f2bf(a[4]) | (f2bf(a[5]) << 16);
        u.w = f2bf(a[6]) | (f2bf(a[7]) << 16);
        *(uint4*)(tgt + (size_t)row * 128 + cl * 8) = u;
      }
    }
  }
}

// ---------------- scans ----------------
__global__ void k_scan_partial(const int* __restrict__ deg, int* __restrict__ bsum, int N) {
  __shared__ int s[256];
  int b = blockIdx.x, t = threadIdx.x;
  int base = b * 1024 + t * 4;
  int v = 0;
#pragma unroll
  for (int i = 0; i < 4; ++i) { int idx = base + i; if (idx < N) v += deg[idx]; }
  s[t] = v; __syncthreads();
  for (int o = 128; o > 0; o >>= 1) { if (t < o) s[t] += s[t + o]; __syncthreads(); }
  if (t == 0) bsum[b] = s[0];
}

__global__ void k_scan_bsums(const int* __restrict__ bsum, int* __restrict__ bpre,
                             int* __restrict__ offsets, int NB, int N) {
  __shared__ int s[128];
  int t = threadIdx.x;
  int v = (t < NB) ? bsum[t] : 0;
  s[t] = v; __syncthreads();
  for (int o = 1; o < 128; o <<= 1) {
    int add = (t >= o) ? s[t - o] : 0;
    __syncthreads();
    s[t] += add;
    __syncthreads();
  }
  if (t < NB) bpre[t] = s[t] - v;
  if (t == NB - 1) offsets[N] = s[t];
}

__global__ void k_scan_final(const int* __restrict__ deg, const int* __restrict__ bpre,
                             int* __restrict__ offsets, int* __restrict__ cursor, int N) {
  __shared__ int s[256];
  int b = blockIdx.x, t = threadIdx.x;
  int base = b * 1024 + t * 4;
  int v[4];
#pragma unroll
  for (int i = 0; i < 4; ++i) { int idx = base + i; v[i] = (idx < N) ? deg[idx] : 0; }
  int tsum = v[0] + v[1] + v[2] + v[3];
  s[t] = tsum; __syncthreads();
  for (int o = 1; o < 256; o <<= 1) {
    int add = (t >= o) ? s[t - o] : 0;
    __syncthreads();
    s[t] += add;
    __syncthreads();
  }
  int run = s[t] - tsum + bpre[b];
#pragma unroll
  for (int i = 0; i < 4; ++i) {
    int idx = base + i;
    if (idx < N) { offsets[idx] = run; cursor[idx] = run; }
    run += v[i];
  }
}

__global__ __launch_bounds__(256) void k_scatter(const int* __restrict__ src,
                                                 const int* __restrict__ dst,
                                                 int* __restrict__ cursor,
                                                 int* __restrict__ csr_src) {
  int xcd = blockIdx.x & 7, chunk = blockIdx.x >> 3;
  int e0 = chunk * 2048 + threadIdx.x;
#pragma unroll
  for (int i = 0; i < 8; ++i) {
    int e = e0 + i * 256;
    if (e < NE) {
      int d = dst[e];
      if (d / OCT == xcd) {
        int pos = atomicAdd(&cursor[d], 1);
        csr_src[pos] = src[e];
      }
    }
  }
}

// ---------------- layer-1 epilogue: h1 = relu(agg(Y1) + Z1 + b1) ----------------
#define ACC8(q)                      \
  do {                               \
    acc[0] += bflo(q.x); acc[1] += bfhi(q.x); \
    acc[2] += bflo(q.y); acc[3] += bfhi(q.y); \
    acc[4] += bflo(q.z); acc[5] += bfhi(q.z); \
    acc[6] += bflo(q.w); acc[7] += bfhi(q.w); \
  } while (0)

__global__ __launch_bounds__(256) void k_agg_relu(const ushort* __restrict__ Y1,
                                                  const ushort* __restrict__ Z1,
                                                  const int* __restrict__ offsets,
                                                  const int* __restrict__ csr,
                                                  const float* __restrict__ bias,
                                                  ushort* __restrict__ h1) {
  int tid = threadIdx.x;
  int sg = tid >> 4, fl = tid & 15;
  int n = blockIdx.x * 16 + sg;
  if (n >= NN) return;
  int o0 = offsets[n], o1 = offsets[n + 1];
  const uint4* X4 = (const uint4*)Y1;  // compact 256B rows (r7: footprint halved)
  float acc[8];
#pragma unroll
  for (int k = 0; k < 8; ++k) acc[k] = 0.f;
  int j = o0;
  if (j + 3 < o1) {
    uint4 q0 = X4[(size_t)csr[j] * 16 + fl];
    uint4 q1 = X4[(size_t)csr[j + 1] * 16 + fl];
    uint4 q2 = X4[(size_t)csr[j + 2] * 16 + fl];
    uint4 q3 = X4[(size_t)csr[j + 3] * 16 + fl];
    j += 4;
    while (j + 3 < o1) {
      uint4 p0 = X4[(size_t)csr[j] * 16 + fl];
      uint4 p1 = X4[(size_t)csr[j + 1] * 16 + fl];
      uint4 p2 = X4[(size_t)csr[j + 2] * 16 + fl];
      uint4 p3 = X4[(size_t)csr[j + 3] * 16 + fl];
      j += 4;
      ACC8(q0); ACC8(q1); ACC8(q2); ACC8(q3);
      q0 = p0; q1 = p1; q2 = p2; q3 = p3;
    }
    ACC8(q0); ACC8(q1); ACC8(q2); ACC8(q3);
  }
  for (; j < o1; ++j) {
    uint4 q = X4[(size_t)csr[j] * 16 + fl];
    ACC8(q);
  }
  uint4 zown = ((const uint4*)Z1)[(size_t)n * 16 + fl];
  float z[8] = {bflo(zown.x), bfhi(zown.x), bflo(zown.y), bfhi(zown.y),
                bflo(zown.z), bfhi(zown.z), bflo(zown.w), bfhi(zown.w)};
  float r[8];
#pragma unroll
  for (int jj = 0; jj < 8; ++jj) {  // stored col fl*8+jj <-> orig col jj*16+fl
    r[jj] = fmaxf(acc[jj] + z[jj] + bias[jj * 16 + fl], 0.f);
  }
  uint4 o;
  o.x = f2bf(r[0]) | (f2bf(r[1]) << 16);
  o.y = f2bf(r[2]) | (f2bf(r[3]) << 16);
  o.z = f2bf(r[4]) | (f2bf(r[5]) << 16);
  o.w = f2bf(r[6]) | (f2bf(r[7]) << 16);
  ((uint4*)h1)[(size_t)n * 16 + fl] = o;
}

// ------- aggregation (128-dim bf16, permutation-transparent) -------
__global__ __launch_bounds__(256) void k_aggbf(const ushort* __restrict__ X,
                                               const int* __restrict__ offsets,
                                               const int* __restrict__ csr,
                                               ushort* __restrict__ out) {
  int tid = threadIdx.x;
  int sg = tid >> 4, fl = tid & 15;
  int n = blockIdx.x * 16 + sg;
  if (n >= NN) return;
  int o0 = offsets[n], o1 = offsets[n + 1];
  const uint4* X4 = (const uint4*)X;
  float acc[8];
#pragma unroll
  for (int k = 0; k < 8; ++k) acc[k] = 0.f;
  int j = o0;
  if (j + 3 < o1) {
    uint4 q0 = X4[(size_t)csr[j] * 16 + fl];
    uint4 q1 = X4[(size_t)csr[j + 1] * 16 + fl];
    uint4 q2 = X4[(size_t)csr[j + 2] * 16 + fl];
    uint4 q3 = X4[(size_t)csr[j + 3] * 16 + fl];
    j += 4;
    while (j + 3 < o1) {
      uint4 p0 = X4[(size_t)csr[j] * 16 + fl];
      uint4 p1 = X4[(size_t)csr[j + 1] * 16 + fl];
      uint4 p2 = X4[(size_t)csr[j + 2] * 16 + fl];
      uint4 p3 = X4[(size_t)csr[j + 3] * 16 + fl];
      j += 4;
      ACC8(q0); ACC8(q1); ACC8(q2); ACC8(q3);
      q0 = p0; q1 = p1; q2 = p2; q3 = p3;
    }
    ACC8(q0); ACC8(q1); ACC8(q2); ACC8(q3);
  }
  for (; j < o1; ++j) {
    uint4 q = X4[(size_t)csr[j] * 16 + fl];
    ACC8(q);
  }
  uint4 o;
  o.x = f2bf(acc[0]) | (f2bf(acc[1]) << 16);
  o.y = f2bf(acc[2]) | (f2bf(acc[3]) << 16);
  o.z = f2bf(acc[4]) | (f2bf(acc[5]) << 16);
  o.w = f2bf(acc[6]) | (f2bf(acc[7]) << 16);
  ((uint4*)out)[(size_t)n * 16 + fl] = o;
}

// ---------- fused layer 2+3: h2 never touches HBM ----------
// 782 blocks x 128 rows, full 256 out cols. One 64KB LDS buffer reused 3x:
//   stage Wr2 -> agg MFMA -> stage Wo2 -> root MFMA -> pack h2 tile (bias+relu,
//   permuted cols, XOR swizzle) -> l3 MFMA from LDS with Wt3 -> y3b/z out.
// Saves the 102 MB h2b HBM round-trip + the l3m dispatch.
__global__ __launch_bounds__(512, 4) void k_gemm2l3(
    const ushort* __restrict__ Aagg, const ushort* __restrict__ Aroot,
    const ushort* __restrict__ Wrelt, const ushort* __restrict__ Wroott,
    const float* __restrict__ bias2, const ushort* __restrict__ Wt3,
    const float* __restrict__ bias3, ushort* __restrict__ y3b, float* __restrict__ z) {
  __shared__ ushort sW[256 * 128];  // 64 KB
  int tid = threadIdx.x;
  int r0 = blockIdx.x * 128;
  int lane = tid & 63, wid = tid >> 6;
  int cl = lane & 15, hi = lane >> 4;
  int arow = r0 + wid * 16 + cl;
  const ushort* pa = Aagg + (size_t)arow * 128 + hi * 8;
  const ushort* pr = Aroot + (size_t)arow * 128 + hi * 8;

  // issue first A loads (agg + root) before the W drain
  bf16x8 Aa[2], Ar[2];
  Aa[0] = *(const bf16x8*)(pa);
  Aa[1] = *(const bf16x8*)(pa + 32);
  Ar[0] = *(const bf16x8*)(pr);
  Ar[1] = *(const bf16x8*)(pr + 32);

  {  // stage Wr2 [256o][128k] -> 64KB, pre-swizzled source
    const char* gw = (const char*)Wrelt;
#pragma unroll
    for (int i = 0; i < 8; ++i) {
      int L = (tid + i * 512) << 4;
      int row = L >> 8;
      int gb = L ^ ((row & 15) << 4);
      __builtin_amdgcn_global_load_lds((const __attribute__((address_space(1))) void*)(gw + gb),
                                       (__attribute__((address_space(3))) void*)((char*)sW + L), 16, 0, 0);
    }
  }
  __syncthreads();

  f32x4 zero = {0.f, 0.f, 0.f, 0.f};
  f32x4 acc[16];
#pragma unroll
  for (int j = 0; j < 16; ++j) acc[j] = zero;

#pragma unroll
  for (int ks = 0; ks < 4; ++ks) {  // agg part
    const int p = ks & 1;
    int kb = ks * 64 + hi * 16;
#pragma unroll
    for (int j = 0; j < 16; ++j) {
      bf16x8 wf = ldfrag(sW, j * 16 + cl, kb);
      acc[j] = __builtin_amdgcn_mfma_f32_16x16x32_bf16(Aa[p], wf, acc[j], 0, 0, 0);
    }
    if (ks < 2) Aa[p] = *(const bf16x8*)(pa + (ks + 2) * 32);
  }
  __syncthreads();  // all waves done reading Wr2

  {  // stage Wo2
    const char* gw = (const char*)Wroott;
#pragma unroll
    for (int i = 0; i < 8; ++i) {
      int L = (tid + i * 512) << 4;
      int row = L >> 8;
      int gb = L ^ ((row & 15) << 4);
      __builtin_amdgcn_global_load_lds((const __attribute__((address_space(1))) void*)(gw + gb),
                                       (__attribute__((address_space(3))) void*)((char*)sW + L), 16, 0, 0);
    }
  }
  __syncthreads();

#pragma unroll
  for (int ks = 0; ks < 4; ++ks) {  // root part
    const int p = ks & 1;
    int kb = ks * 64 + hi * 16;
#pragma unroll
    for (int j = 0; j < 16; ++j) {
      bf16x8 wf = ldfrag(sW, j * 16 + cl, kb);
      acc[j] = __builtin_amdgcn_mfma_f32_16x16x32_bf16(Ar[p], wf, acc[j], 0, 0, 0);
    }
    if (ks < 2) Ar[p] = *(const bf16x8*)(pr + (ks + 2) * 32);
  }
  __syncthreads();  // all waves done reading Wo2

  // pack h2 tile into LDS: stored col p = cl*16+j (orig (p&15)*16+(p>>4)),
  // rows 512B, XOR-swizzle ((row&15)<<4) on 16B slots
  {
    float bv[16];
#pragma unroll
    for (int j = 0; j < 16; ++j) bv[j] = bias2[j * 16 + cl];
#pragma unroll
    for (int reg = 0; reg < 4; ++reg) {
      int rr = hi * 4 + reg;  // row & 15
      float v[16];
#pragma unroll
      for (int j = 0; j < 16; ++j) v[j] = fmaxf(acc[j][reg] + bv[j], 0.f);
      uint4 a, bq;
      a.x = f2bf(v[0]) | (f2bf(v[1]) << 16);
      a.y = f2bf(v[2]) | (f2bf(v[3]) << 16);
      a.z = f2bf(v[4]) | (f2bf(v[5]) << 16);
      a.w = f2bf(v[6]) | (f2bf(v[7]) << 16);
      bq.x = f2bf(v[8]) | (f2bf(v[9]) << 16);
      bq.y = f2bf(v[10]) | (f2bf(v[11]) << 16);
      bq.z = f2bf(v[12]) | (f2bf(v[13]) << 16);
      bq.w = f2bf(v[14]) | (f2bf(v[15]) << 16);
      int rowb = (wid * 16 + rr) * 512;
      *(uint4*)((char*)sW + rowb + ((cl * 32 + 0) ^ (rr << 4))) = a;
      *(uint4*)((char*)sW + rowb + ((cl * 32 + 16) ^ (rr << 4))) = bq;
    }
  }
  __syncthreads();

  // l3: wave reads its own 16-row panel back as A-frags (row = lane&15 = cl)
  f32x4 ay = zero, az = zero;
  const ushort* w3a = Wt3 + cl * 256 + hi * 8;         // y3 outs 0..15
  const ushort* w3b = Wt3 + (16 + cl) * 256 + hi * 8;  // z outs 0..15
#pragma unroll
  for (int ks = 0; ks < 8; ++ks) {
    int c = ks * 4 + hi;  // 16B chunk in 512B row
    bf16x8 a = *(const bf16x8*)((const char*)sW + (wid * 16 + cl) * 512 + ((c * 16) ^ (cl << 4)));
    bf16x8 b0 = *(const bf16x8*)(w3a + ks * 32);
    bf16x8 b1 = *(const bf16x8*)(w3b + ks * 32);
    ay = __builtin_amdgcn_mfma_f32_16x16x32_bf16(a, b0, ay, 0, 0, 0);
    az = __builtin_amdgcn_mfma_f32_16x16x32_bf16(a, b1, az, 0, 0, 0);
  }
  float bv3 = bias3[cl];
#pragma unroll
  for (int reg = 0; reg < 4; ++reg) {
    int row = r0 + wid * 16 + hi * 4 + reg;
    if (row < NN) {
      y3b[(size_t)row * 16 + cl] = (ushort)f2bf(ay[reg]);
      z[(size_t)row * 16 + cl] = az[reg] + bv3;
    }
  }
}

// ---------------- fused: out = log_softmax(z + segsum(y3b[src])) ----------------
__global__ void k_agg16lsm(const int* __restrict__ offsets, const int* __restrict__ csr,
                           const ushort* __restrict__ y3b, float* __restrict__ out) {
  int t = blockIdx.x * 256 + threadIdx.x;  // (node, uint-pair) : 8 lanes per node
  if (t >= NN * 8) return;
  int n = t >> 3, g = t & 7;
  int o0 = offsets[n], o1 = offsets[n + 1];
  float a0 = 0.f, a1 = 0.f;
  const uint* Y = (const uint*)y3b;
  for (int j = o0; j < o1; ++j) {
    uint u = Y[(size_t)csr[j] * 8 + g];
    a0 += bflo(u); a1 += bfhi(u);
  }
  float v0 = out[n * 16 + g * 2] + a0;
  float v1 = out[n * 16 + g * 2 + 1] + a1;
  float m = fmaxf(v0, v1);
#pragma unroll
  for (int mask = 1; mask < 8; mask <<= 1) m = fmaxf(m, __shfl_xor(m, mask));
  float s = __expf(v0 - m) + __expf(v1 - m);
#pragma unroll
  for (int mask = 1; mask < 8; mask <<= 1) s += __shfl_xor(s, mask);
  float ls = __logf(s);
  out[n * 16 + g * 2] = v0 - m - ls;
  out[n * 16 + g * 2 + 1] = v1 - m - ls;
}

extern "C" void kernel_launch(void* const* d_in, const int* in_sizes, int n_in,
                              void* d_out, int out_size, void* d_ws, size_t ws_size,
                              hipStream_t stream) {
  const float* x = (const float*)d_in[0];
  const int* ei = (const int*)d_in[1];  // [2][NE]: row0=src, row1=dst
  const float* Wrel1 = (const float*)d_in[2];
  const float* Wroot1 = (const float*)d_in[3];
  const float* b1 = (const float*)d_in[4];
  const float* Wrel2 = (const float*)d_in[5];
  const float* Wroot2 = (const float*)d_in[6];
  const float* b2 = (const float*)d_in[7];
  const float* Wrel3 = (const float*)d_in[8];
  const float* Wroot3 = (const float*)d_in[9];
  const float* b3 = (const float*)d_in[10];
  float* out = (float*)d_out;

  char* ws = (char*)d_ws;
  size_t off = 0;
  auto alloc = [&](size_t bytes) {
    void* p = ws + off;
    off += (bytes + 255) / 256 * 256;
    return p;
  };
  int* deg = (int*)alloc((size_t)NN * 4);
  int* offsets = (int*)alloc((size_t)(NN + 1) * 4);
  int* cursor = (int*)alloc((size_t)NN * 4);
  int* bsum = (int*)alloc(128 * 4);
  int* bpre = (int*)alloc(128 * 4);
  int* csr = (int*)alloc((size_t)NE * 4);
  ushort* Y1 = (ushort*)alloc((size_t)NN * 128 * 2);   // x@Wrel1, permuted cols
  ushort* Z1 = (ushort*)alloc((size_t)NN * 128 * 2);   // x@Wroot1, permuted cols
  ushort* aggb = (ushort*)alloc((size_t)NPAD * 128 * 2);
  ushort* h1b = (ushort*)alloc((size_t)NPAD * 128 * 2);
  ushort* y3b = (ushort*)alloc((size_t)NN * 16 * 2);
  ushort* wt = (ushort*)alloc((size_t)106496 * 2);
  ushort *Wr2t = wt + 32768, *Wo2t = wt + 65536;
  ushort* Wt3 = wt + 98304;

  const int* src = ei;
  const int* dst = ei + NE;

  // fused: gemm1' (X@[Wr1|Wo1] -> Y1,Z1) + hist + cvt_w(W2,Wt3)
  hipMemsetAsync(deg, 0, (size_t)NN * 4, stream);
  k_fuse1<<<2496, 512, 0, stream>>>(x, Y1, Z1, Wrel1, Wroot1, Wrel2, Wroot2, Wrel3,
                                    Wroot3, wt, dst, deg);

  // CSR build
  int NB = (NN + 1023) / 1024;  // 98
  k_scan_partial<<<NB, 256, 0, stream>>>(deg, bsum, NN);
  k_scan_bsums<<<1, 128, 0, stream>>>(bsum, bpre, offsets, NB, NN);
  k_scan_final<<<NB, 256, 0, stream>>>(deg, bpre, offsets, cursor, NN);
  int nchunk = (NE + 2047) / 2048;  // 391
  k_scatter<<<8 * nchunk, 256, 0, stream>>>(src, dst, cursor, csr);

  // layer 1: h1 = relu(agg(Y1) + Z1 + b1)
  k_agg_relu<<<NN / 16, 256, 0, stream>>>(Y1, Z1, offsets, csr, b1, h1b);
  // layer 2+3 fused: agg -> (gemm2 + l3) with h2 LDS-resident
  k_aggbf<<<(NN + 15) / 16, 256, 0, stream>>>(h1b, offsets, csr, aggb);
  k_gemm2l3<<<NPAD / 128, 512, 0, stream>>>(aggb, h1b, Wr2t, Wo2t, b2, Wt3, b3, y3b, out);
  // epilogue
  k_agg16lsm<<<(NN * 8 + 255) / 256, 256, 0, stream>>>(offsets, csr, y3b, out);
}